// Round 9
// baseline (1172.556 us; speedup 1.0000x reference)
//
#include <hip/hip_runtime.h>
#include <hip/hip_bf16.h>

// BRITS-style RNN (B=4096, T=256, D=36, H=64) on gfx950.
// R9: R8's 2-barrier row-sliced structure + h-independent precompute + reg diet.
// Key identity: gamma(t) needs only delta(t); beta(t) needs only [gamma,mask](t).
// So S-waves compute Gm/gamma/comb/beta for step t+1 in P2 (overlapping G's
// gi-kt2/3+GRU), leaving S-P1 = vx(2 MFMA)->vc1->feat(6 MFMA)->impute(beta in
// regs)->vc2: one LDS round-trip on the h-critical path. G-P1 = gh(6, whh from
// LDS) + gi-kt0/kt1(6) + staging; G-P2 = gi-kt2/kt3(6) + GRU.
// Register diet: whh (per-G-wave) and comb (wave-invariant) B-frags in LDS ->
// ~105 VGPR appetite; __launch_bounds__(512,4) requests 2 blocks/CU (16 waves,
// <=128 total regs/wave). LDS 78.4KB -> 2 blocks = 157KB <= 160KB.

#define Bsz 4096
#define Tn  256
#define Dn  36
#define ROWS 16
#define EPSf 1e-5f
#define VMST 38

using f32x4 = __attribute__((ext_vector_type(4))) float;
using s8    = __attribute__((ext_vector_type(8))) short;

__device__ __forceinline__ short f2bf(float x) {
  return (short)__bfloat16_as_ushort(__float2bfloat16(x));
}
__device__ __forceinline__ float sigf(float x) { return 1.f / (1.f + __expf(-x)); }
__device__ __forceinline__ float tanhfast(float x) { return 1.f - 2.f / (1.f + __expf(2.f * x)); }
// fragment-linear offset for element (row, k) of an MFMA A-tile (16 rows, bf16)
__device__ __forceinline__ int fragoff(int row, int k) {
  return ((k >> 5) << 9) + (((k >> 3) & 3) << 7) + (row << 3) + (k & 7);
}
// v[s] for wave-uniform runtime s without scratch
__device__ __forceinline__ float selq(f32x4 v, int s) {
  float a = (s & 1) ? v[1] : v[0];
  float b = (s & 1) ? v[3] : v[2];
  return (s & 2) ? b : a;
}
#define MFMA __builtin_amdgcn_mfma_f32_16x16x32_bf16

// ---------------- prepass: rmsum[t] = 1/(sum(masks[:,t,:]) + EPS) -------------
__global__ void msum_k(const float4* __restrict__ masks4, float* __restrict__ rmsum) {
  int t = blockIdx.x;
  float s = 0.f;
  for (int r = threadIdx.x; r < Bsz; r += 256) {
    const float4* mp = masks4 + ((size_t)r * Tn + t) * 9;
    #pragma unroll
    for (int j = 0; j < 9; ++j) { float4 v = mp[j]; s += v.x + v.y + v.z + v.w; }
  }
  __shared__ float red[256];
  red[threadIdx.x] = s;
  __syncthreads();
  for (int k = 128; k > 0; k >>= 1) {
    if (threadIdx.x < k) red[threadIdx.x] += red[threadIdx.x + k];
    __syncthreads();
  }
  if (threadIdx.x == 0) rmsum[t] = 1.f / (red[0] + EPSf);
}

// ---------------- main ---------------------------------------------------------
__global__ __launch_bounds__(512, 4) void brits_main(
    const float* __restrict__ values, const float* __restrict__ masks,
    const float* __restrict__ deltas, const float* __restrict__ label,
    const float* __restrict__ is_train,
    const float* __restrict__ W_ih, const float* __restrict__ W_hh,
    const float* __restrict__ b_ih, const float* __restrict__ b_hh,
    const float* __restrict__ hist_W, const float* __restrict__ hist_b,
    const float* __restrict__ feat_W, const float* __restrict__ feat_b,
    const float* __restrict__ decay_W, const float* __restrict__ decay_b,
    const float* __restrict__ comb_W, const float* __restrict__ comb_b,
    const float* __restrict__ out_W, const float* __restrict__ out_b,
    float* __restrict__ out, const float* __restrict__ rmsum,
    float* __restrict__ ws_acc /* [0] il, [1] cls, [2] wsum */) {

  __shared__ __align__(16) float2 vm_s[2][ROWS * VMST];  // (value, mask)
  __shared__ __align__(16) short hbuf[1024];        // h bf16, K=64 frag-linear
  __shared__ __align__(16) short dbuf[2][1024];     // delta, parity-buffered
  __shared__ __align__(16) short xbuf[2][2048];     // [mask|gamma|vc2|pad] K=128
  __shared__ __align__(16) short vcbuf[4][1024];    // per-S-wave private vc1
  __shared__ __align__(16) short cxbuf[4][1536];    // per-S-wave [gamma|mask] K=96
  __shared__ __align__(16) short whh_l[24 * 512];   // [gw][g][kt] B-frags, 24KB
  __shared__ __align__(16) short comb_l[9 * 512];   // [t3][kt] B-frags, 9KB
  __shared__ float red16[16];

  const int tid  = threadIdx.x;
  const int w    = tid >> 6;        // wave 0..7
  const int lane = tid & 63;
  const int lc   = lane & 15;
  const int r4   = lane >> 4;
  const int row0 = blockIdx.x * ROWS;
  const int k0b  = r4 * 8;
  const int lw8  = lane * 8;

  const bool isG = (w < 4);
  const int  sW  = isG ? 0 : (w - 4);
  const int  dim = 16 * (isG ? w : 0) + lc;
  const int  myrow = 4 * r4 + sW;

  // ---- role-overlaid VGPR weight fragments ----
  // G: bf[0..11] = wih (xbuf k-space remap), gate g occupies [g*4 .. g*4+3]
  // S: bf[0..5]=dec, bf[6..11]=feat(zero diag), bf[12..13]=hist(all cols)
  s8 bf[14];
  #pragma unroll
  for (int i = 0; i < 14; ++i) bf[i] = (s8)(short)0;

  if (isG) {
    #pragma unroll
    for (int g = 0; g < 3; ++g) {
      const int n = 64 * g + dim;
      #pragma unroll
      for (int kt = 0; kt < 4; ++kt) {
        s8 f;
        #pragma unroll
        for (int e = 0; e < 8; ++e) {
          int xk = k0b + 32 * kt + e;
          // xbuf k-space [mask(0:36)|gamma(36:72)|vc2(72:108)|pad]
          // W_ih cols    [vc(0:36)|mask(36:72)|gamma(72:108)]
          float wv = 0.f;
          if (xk < 72) wv = W_ih[n * 108 + 36 + xk];
          else if (xk < 108) wv = W_ih[n * 108 + xk - 72];
          f[e] = f2bf(wv);
        }
        bf[g * 4 + kt] = f;
      }
      // whh -> LDS (consumed in G-P1, off critical path)
      #pragma unroll
      for (int kt = 0; kt < 2; ++kt) {
        s8 f;
        #pragma unroll
        for (int e = 0; e < 8; ++e) f[e] = f2bf(W_hh[n * 64 + k0b + 32 * kt + e]);
        *(s8*)&whh_l[(w * 6 + g * 2 + kt) * 512 + lw8] = f;
      }
    }
  } else {
    #pragma unroll
    for (int t3 = 0; t3 < 3; ++t3) {
      const int col = 16 * t3 + lc;
      const bool cok = (col < Dn);
      #pragma unroll
      for (int kt = 0; kt < 2; ++kt) {
        s8 fd, ff;
        #pragma unroll
        for (int e = 0; e < 8; ++e) {
          int k = k0b + 32 * kt + e;
          fd[e] = f2bf((cok && k < Dn) ? decay_W[col * Dn + k] : 0.f);
          ff[e] = f2bf((cok && k < Dn && k != col) ? feat_W[col * Dn + k] : 0.f);
        }
        bf[t3 * 2 + kt] = fd;
        bf[6 + t3 * 2 + kt] = ff;
      }
    }
    #pragma unroll
    for (int kt = 0; kt < 2; ++kt) {
      s8 f;
      #pragma unroll
      for (int e = 0; e < 8; ++e) f[e] = f2bf(hist_W[k0b + 32 * kt + e]);
      bf[12 + kt] = f;
    }
    if (w == 4) {   // comb B-frags are wave-invariant -> one writer
      #pragma unroll
      for (int t3 = 0; t3 < 3; ++t3) {
        const int col = 16 * t3 + lc;
        const bool cok = (col < Dn);
        #pragma unroll
        for (int kt = 0; kt < 3; ++kt) {
          s8 f;
          #pragma unroll
          for (int e = 0; e < 8; ++e) {
            int k = k0b + 32 * kt + e;  // cxbuf k-space [gamma(0:36)|mask(36:72)]
            f[e] = f2bf((cok && k < 72) ? comb_W[col * 72 + k] : 0.f);
          }
          *(s8*)&comb_l[(t3 * 3 + kt) * 512 + lw8] = f;
        }
      }
    }
  }

  // per-lane constants
  float db3[3] = {0,0,0}, fb3[3] = {0,0,0}, cb3[3] = {0,0,0};
  float br = 0.f, bz = 0.f, bin_ = 0.f, bhn = 0.f, ow = 0.f;
  if (isG) {
    br   = b_ih[dim] + b_hh[dim];
    bz   = b_ih[64 + dim] + b_hh[64 + dim];
    bin_ = b_ih[128 + dim];
    bhn  = b_hh[128 + dim];
    ow   = out_W[dim];
  } else {
    #pragma unroll
    for (int t3 = 0; t3 < 3; ++t3) {
      int col = 16 * t3 + lc;
      if (col < Dn) { db3[t3] = decay_b[col]; fb3[t3] = feat_b[col]; cb3[t3] = comb_b[col]; }
    }
  }
  const float histb = hist_b[0];
  const int hb = fragoff(0, dim);

  // staging geometry (G waves, tids 0..143): 16 rows x 9 quads
  const bool stg = (tid < 144);
  const int srow = tid / 9;
  const int squad = tid - srow * 9;
  const size_t sbase = ((size_t)(row0 + srow) * Tn) * Dn + squad * 4;
  const int sfo = fragoff(srow, squad * 4);
  const int svo = srow * VMST + squad * 4;

  // S mask->cxbuf geometry (lane < 36)
  const int mrow = 4 * (lane / 9) + sW;
  const int mc0  = (lane % 9) * 4;

  // ---- init LDS ----
  for (int i = tid; i < 1024; i += 512) {
    hbuf[i] = 0; dbuf[0][i] = 0; dbuf[1][i] = 0;
    vcbuf[0][i] = 0; vcbuf[1][i] = 0; vcbuf[2][i] = 0; vcbuf[3][i] = 0;
  }
  for (int i = tid; i < 2048; i += 512) { xbuf[0][i] = 0; xbuf[1][i] = 0; }
  for (int i = tid; i < 1536; i += 512) {
    cxbuf[0][i] = 0; cxbuf[1][i] = 0; cxbuf[2][i] = 0; cxbuf[3][i] = 0;
  }
  __syncthreads();

  // ---- prologue: stage t=0 (parity 0), prefetch t=1 ----
  float4 pv = {0,0,0,0}, pm = {0,0,0,0}, pd = {0,0,0,0};
  if (stg) {
    float4 v0 = *(const float4*)&values[sbase];
    float4 m0 = *(const float4*)&masks[sbase];
    float4 d0 = *(const float4*)&deltas[sbase];
    *(float4*)&vm_s[0][svo]     = make_float4(v0.x, m0.x, v0.y, m0.y);
    *(float4*)&vm_s[0][svo + 2] = make_float4(v0.z, m0.z, v0.w, m0.w);
    union { short s[4]; uint2 u; } td, tm;
    td.s[0]=f2bf(d0.x); td.s[1]=f2bf(d0.y); td.s[2]=f2bf(d0.z); td.s[3]=f2bf(d0.w);
    tm.s[0]=f2bf(m0.x); tm.s[1]=f2bf(m0.y); tm.s[2]=f2bf(m0.z); tm.s[3]=f2bf(m0.w);
    *(uint2*)&dbuf[0][sfo] = td.u;
    *(uint2*)&xbuf[0][sfo] = tm.u;
    pv = *(const float4*)&values[sbase + Dn];
    pm = *(const float4*)&masks[sbase + Dn];
    pd = *(const float4*)&deltas[sbase + Dn];
  }
  __syncthreads();

  float bq[3] = {0.f, 0.f, 0.f};    // precomputed beta for the CURRENT step
  // S precompute for t=0: Gm/gamma/comb/beta from dbuf[0], vm_s[0]
  if (!isG) {
    s8 ad0 = *(const s8*)&dbuf[0][lw8];
    s8 ad1 = *(const s8*)&dbuf[0][512 + lw8];
    f32x4 G0 = {0,0,0,0}, G1 = {0,0,0,0}, G2 = {0,0,0,0};
    G0 = MFMA(ad0, bf[0], G0, 0,0,0); G0 = MFMA(ad1, bf[1], G0, 0,0,0);
    G1 = MFMA(ad0, bf[2], G1, 0,0,0); G1 = MFMA(ad1, bf[3], G1, 0,0,0);
    G2 = MFMA(ad0, bf[4], G2, 0,0,0); G2 = MFMA(ad1, bf[5], G2, 0,0,0);
    #pragma unroll
    for (int t3 = 0; t3 < 3; ++t3) {
      int col = 16 * t3 + lc;
      if (col < Dn) {
        float gm = (t3==0) ? selq(G0,sW) : (t3==1) ? selq(G1,sW) : selq(G2,sW);
        short gbv = f2bf(__expf(-fmaxf(gm + db3[t3], 0.f)));
        xbuf[0][fragoff(myrow, 36 + col)] = gbv;
        cxbuf[sW][fragoff(myrow, col)] = gbv;
      }
    }
    if (lane < 36) {
      #pragma unroll
      for (int j = 0; j < 4; ++j)
        cxbuf[sW][fragoff(mrow, 36 + mc0 + j)] = f2bf(vm_s[0][mrow * VMST + mc0 + j].y);
    }
    s8 ac0 = *(const s8*)&cxbuf[sW][lw8];
    s8 ac1 = *(const s8*)&cxbuf[sW][512 + lw8];
    s8 ac2 = *(const s8*)&cxbuf[sW][1024 + lw8];
    f32x4 B0 = {0,0,0,0}, B1 = {0,0,0,0}, B2 = {0,0,0,0};
    B0 = MFMA(ac0, *(const s8*)&comb_l[0*512+lw8], B0, 0,0,0);
    B0 = MFMA(ac1, *(const s8*)&comb_l[1*512+lw8], B0, 0,0,0);
    B0 = MFMA(ac2, *(const s8*)&comb_l[2*512+lw8], B0, 0,0,0);
    B1 = MFMA(ac0, *(const s8*)&comb_l[3*512+lw8], B1, 0,0,0);
    B1 = MFMA(ac1, *(const s8*)&comb_l[4*512+lw8], B1, 0,0,0);
    B1 = MFMA(ac2, *(const s8*)&comb_l[5*512+lw8], B1, 0,0,0);
    B2 = MFMA(ac0, *(const s8*)&comb_l[6*512+lw8], B2, 0,0,0);
    B2 = MFMA(ac1, *(const s8*)&comb_l[7*512+lw8], B2, 0,0,0);
    B2 = MFMA(ac2, *(const s8*)&comb_l[8*512+lw8], B2, 0,0,0);
    bq[0] = sigf(selq(B0,sW) + cb3[0]);
    bq[1] = sigf(selq(B1,sW) + cb3[1]);
    bq[2] = sigf(selq(B2,sW) + cb3[2]);
  }

  float hreg[4] = {0.f, 0.f, 0.f, 0.f};
  float lacc[4] = {0.f, 0.f, 0.f, 0.f};
  float il = 0.f;
  __syncthreads();

  #pragma unroll 1
  for (int t = 0; t < Tn; ++t) {
    const float srm = rmsum[t];
    const int p = t & 1;
    f32x4 A0 = {0,0,0,0}, A1 = {0,0,0,0}, A2 = {0,0,0,0}, A3 = {0,0,0,0};

    // ================ P1 ================
    if (isG) {
      const int wb = w * 6 * 512;
      s8 ah0 = *(const s8*)&hbuf[lw8];
      s8 ah1 = *(const s8*)&hbuf[512 + lw8];
      A0 = MFMA(ah0, *(const s8*)&whh_l[wb + lw8],        A0, 0,0,0);
      A0 = MFMA(ah1, *(const s8*)&whh_l[wb + 512 + lw8],  A0, 0,0,0);
      A1 = MFMA(ah0, *(const s8*)&whh_l[wb + 1024 + lw8], A1, 0,0,0);
      A1 = MFMA(ah1, *(const s8*)&whh_l[wb + 1536 + lw8], A1, 0,0,0);
      A3 = MFMA(ah0, *(const s8*)&whh_l[wb + 2048 + lw8], A3, 0,0,0);
      A3 = MFMA(ah1, *(const s8*)&whh_l[wb + 2560 + lw8], A3, 0,0,0);
      s8 ax0 = *(const s8*)&xbuf[p][lw8];
      s8 ax1 = *(const s8*)&xbuf[p][512 + lw8];
      A0 = MFMA(ax0, bf[0], A0, 0,0,0); A0 = MFMA(ax1, bf[1], A0, 0,0,0);
      A1 = MFMA(ax0, bf[4], A1, 0,0,0); A1 = MFMA(ax1, bf[5], A1, 0,0,0);
      A2 = MFMA(ax0, bf[8], A2, 0,0,0); A2 = MFMA(ax1, bf[9], A2, 0,0,0);
      // stage t+1 into parity p^1
      if (stg && t + 1 < Tn) {
        *(float4*)&vm_s[p ^ 1][svo]     = make_float4(pv.x, pm.x, pv.y, pm.y);
        *(float4*)&vm_s[p ^ 1][svo + 2] = make_float4(pv.z, pm.z, pv.w, pm.w);
        union { short s[4]; uint2 u; } td, tm;
        td.s[0]=f2bf(pd.x); td.s[1]=f2bf(pd.y); td.s[2]=f2bf(pd.z); td.s[3]=f2bf(pd.w);
        tm.s[0]=f2bf(pm.x); tm.s[1]=f2bf(pm.y); tm.s[2]=f2bf(pm.z); tm.s[3]=f2bf(pm.w);
        *(uint2*)&dbuf[p ^ 1][sfo] = td.u;
        *(uint2*)&xbuf[p ^ 1][sfo] = tm.u;
      }
      if (stg && t + 2 < Tn) {
        size_t o = sbase + (size_t)(t + 2) * Dn;
        pv = *(const float4*)&values[o];
        pm = *(const float4*)&masks[o];
        pd = *(const float4*)&deltas[o];
      }
    } else {
      // ---- S: h-critical chain only (beta already in regs) ----
      s8 ah0 = *(const s8*)&hbuf[lw8];
      s8 ah1 = *(const s8*)&hbuf[512 + lw8];
      f32x4 X = {0,0,0,0};
      X = MFMA(ah0, bf[12], X, 0,0,0);
      X = MFMA(ah1, bf[13], X, 0,0,0);
      const float vx = selq(X, sW) + histb;
      float v3[3], m3[3];
      #pragma unroll
      for (int t3 = 0; t3 < 3; ++t3) {
        int col = 16 * t3 + lc;
        v3[t3] = 0.f; m3[t3] = 0.f;
        if (col < Dn) {
          float2 vm = vm_s[p][myrow * VMST + col];
          v3[t3] = vm.x; m3[t3] = vm.y;
          il += srm * fabsf(vx - vm.x) * vm.y;
          vcbuf[sW][fragoff(myrow, col)] = f2bf(vm.y * vm.x + (1.f - vm.y) * vx);
        }
      }
      s8 av0 = *(const s8*)&vcbuf[sW][lw8];
      s8 av1 = *(const s8*)&vcbuf[sW][512 + lw8];
      f32x4 Z0 = {0,0,0,0}, Z1 = {0,0,0,0}, Z2 = {0,0,0,0};
      Z0 = MFMA(av0, bf[6],  Z0, 0,0,0); Z0 = MFMA(av1, bf[7],  Z0, 0,0,0);
      Z1 = MFMA(av0, bf[8],  Z1, 0,0,0); Z1 = MFMA(av1, bf[9],  Z1, 0,0,0);
      Z2 = MFMA(av0, bf[10], Z2, 0,0,0); Z2 = MFMA(av1, bf[11], Z2, 0,0,0);
      #pragma unroll
      for (int t3 = 0; t3 < 3; ++t3) {
        int col = 16 * t3 + lc;
        if (col < Dn) {
          float vz = ((t3==0) ? selq(Z0,sW) : (t3==1) ? selq(Z1,sW) : selq(Z2,sW)) + fb3[t3];
          il += srm * fabsf(vz - v3[t3]) * m3[t3];
          float vh = vz * bq[t3] + vx * (1.f - bq[t3]);
          il += srm * fabsf(vh - v3[t3]) * m3[t3];
          float vc2 = m3[t3] * v3[t3] + (1.f - m3[t3]) * vh;
          out[1 + ((size_t)(row0 + myrow) * Tn + t) * Dn + col] = vc2;
          xbuf[p][fragoff(myrow, 72 + col)] = f2bf(vc2);
        }
      }
    }
    __syncthreads();  // b1: vc2 + staged t+1 visible

    // ================ P2 ================
    if (isG) {
      s8 ax2 = *(const s8*)&xbuf[p][1024 + lw8];
      s8 ax3 = *(const s8*)&xbuf[p][1536 + lw8];
      A0 = MFMA(ax2, bf[2],  A0, 0,0,0); A0 = MFMA(ax3, bf[3],  A0, 0,0,0);
      A1 = MFMA(ax2, bf[6],  A1, 0,0,0); A1 = MFMA(ax3, bf[7],  A1, 0,0,0);
      A2 = MFMA(ax2, bf[10], A2, 0,0,0); A2 = MFMA(ax3, bf[11], A2, 0,0,0);
      #pragma unroll
      for (int q = 0; q < 4; ++q) {
        float rg = sigf(A0[q] + br);
        float zg = sigf(A1[q] + bz);
        float ng = tanhfast(A2[q] + bin_ + rg * (A3[q] + bhn));
        float hn = (1.f - zg) * ng + zg * hreg[q];
        hreg[q] = hn;
        lacc[q] += hn * ow;
        hbuf[hb + (r4 * 4 + q) * 8] = f2bf(hn);
      }
    } else if (t + 1 < Tn) {
      // ---- S: precompute Gm/gamma/comb/beta for t+1 (h-independent) ----
      s8 ad0 = *(const s8*)&dbuf[p ^ 1][lw8];
      s8 ad1 = *(const s8*)&dbuf[p ^ 1][512 + lw8];
      f32x4 G0 = {0,0,0,0}, G1 = {0,0,0,0}, G2 = {0,0,0,0};
      G0 = MFMA(ad0, bf[0], G0, 0,0,0); G0 = MFMA(ad1, bf[1], G0, 0,0,0);
      G1 = MFMA(ad0, bf[2], G1, 0,0,0); G1 = MFMA(ad1, bf[3], G1, 0,0,0);
      G2 = MFMA(ad0, bf[4], G2, 0,0,0); G2 = MFMA(ad1, bf[5], G2, 0,0,0);
      #pragma unroll
      for (int t3 = 0; t3 < 3; ++t3) {
        int col = 16 * t3 + lc;
        if (col < Dn) {
          float gm = (t3==0) ? selq(G0,sW) : (t3==1) ? selq(G1,sW) : selq(G2,sW);
          short gbv = f2bf(__expf(-fmaxf(gm + db3[t3], 0.f)));
          xbuf[p ^ 1][fragoff(myrow, 36 + col)] = gbv;
          cxbuf[sW][fragoff(myrow, col)] = gbv;
        }
      }
      if (lane < 36) {
        #pragma unroll
        for (int j = 0; j < 4; ++j)
          cxbuf[sW][fragoff(mrow, 36 + mc0 + j)] =
              f2bf(vm_s[p ^ 1][mrow * VMST + mc0 + j].y);
      }
      s8 ac0 = *(const s8*)&cxbuf[sW][lw8];
      s8 ac1 = *(const s8*)&cxbuf[sW][512 + lw8];
      s8 ac2 = *(const s8*)&cxbuf[sW][1024 + lw8];
      f32x4 B0 = {0,0,0,0}, B1 = {0,0,0,0}, B2 = {0,0,0,0};
      B0 = MFMA(ac0, *(const s8*)&comb_l[0*512+lw8], B0, 0,0,0);
      B0 = MFMA(ac1, *(const s8*)&comb_l[1*512+lw8], B0, 0,0,0);
      B0 = MFMA(ac2, *(const s8*)&comb_l[2*512+lw8], B0, 0,0,0);
      B1 = MFMA(ac0, *(const s8*)&comb_l[3*512+lw8], B1, 0,0,0);
      B1 = MFMA(ac1, *(const s8*)&comb_l[4*512+lw8], B1, 0,0,0);
      B1 = MFMA(ac2, *(const s8*)&comb_l[5*512+lw8], B1, 0,0,0);
      B2 = MFMA(ac0, *(const s8*)&comb_l[6*512+lw8], B2, 0,0,0);
      B2 = MFMA(ac1, *(const s8*)&comb_l[7*512+lw8], B2, 0,0,0);
      B2 = MFMA(ac2, *(const s8*)&comb_l[8*512+lw8], B2, 0,0,0);
      bq[0] = sigf(selq(B0,sW) + cb3[0]);
      bq[1] = sigf(selq(B1,sW) + cb3[1]);
      bq[2] = sigf(selq(B2,sW) + cb3[2]);
    }
    __syncthreads();  // b2: h(t) + gamma(t+1) visible
  }

  // ---- epilogue: reduce il, logits, pred, class loss ----
  float* red_s = (float*)whh_l;   // whh_l dead after the loop
  red_s[tid] = il;
  __syncthreads();
  for (int k = 256; k > 0; k >>= 1) {
    if (tid < k) red_s[tid] += red_s[tid + k];
    __syncthreads();
  }
  if (tid == 0) atomicAdd(&ws_acc[0], red_s[0]);
  if (tid < 16) red16[tid] = 0.f;
  __syncthreads();
  if (isG) {
    #pragma unroll
    for (int q = 0; q < 4; ++q) atomicAdd(&red16[r4 * 4 + q], lacc[q]);
  }
  __syncthreads();

  if (tid < ROWS) {
    float lg = red16[tid] / (float)Tn + out_b[0];
    int rg = row0 + tid;
    float pred = sigf(lg);
    out[1 + (size_t)Bsz * Tn * Dn + rg] = pred;
    float y = label[rg], wt = is_train[rg];
    float bce = fmaxf(lg, 0.f) - lg * y + log1pf(__expf(-fabsf(lg)));
    atomicAdd(&ws_acc[1], bce * wt);
    atomicAdd(&ws_acc[2], wt);
  }
}

// ---------------- finalize loss -------------------------------------------------
__global__ void fin_k(const float* __restrict__ ws, float* __restrict__ out) {
  out[0] = ws[1] / (ws[2] + EPSf) + ws[0] / (float)Tn;
}

extern "C" void kernel_launch(void* const* d_in, const int* in_sizes, int n_in,
                              void* d_out, int out_size, void* d_ws, size_t ws_size,
                              hipStream_t stream) {
  const float* values   = (const float*)d_in[0];
  const float* masks    = (const float*)d_in[1];
  const float* deltas   = (const float*)d_in[2];
  const float* label    = (const float*)d_in[3];
  const float* is_train = (const float*)d_in[4];
  const float* W_ih     = (const float*)d_in[5];
  const float* W_hh     = (const float*)d_in[6];
  const float* b_ih     = (const float*)d_in[7];
  const float* b_hh     = (const float*)d_in[8];
  const float* hist_W   = (const float*)d_in[9];
  const float* hist_b   = (const float*)d_in[10];
  const float* feat_W   = (const float*)d_in[11];
  const float* feat_b   = (const float*)d_in[12];
  const float* decay_W  = (const float*)d_in[13];
  const float* decay_b  = (const float*)d_in[14];
  const float* comb_W   = (const float*)d_in[15];
  const float* comb_b   = (const float*)d_in[16];
  const float* out_W    = (const float*)d_in[17];
  const float* out_b    = (const float*)d_in[18];

  float* ws = (float*)d_ws;
  float* rmsum = ws + 4;
  float* out = (float*)d_out;

  hipMemsetAsync(d_ws, 0, 16, stream);
  msum_k<<<Tn, 256, 0, stream>>>((const float4*)masks, rmsum);
  brits_main<<<Bsz / ROWS, 512, 0, stream>>>(
      values, masks, deltas, label, is_train, W_ih, W_hh, b_ih, b_hh,
      hist_W, hist_b, feat_W, feat_b, decay_W, decay_b, comb_W, comb_b,
      out_W, out_b, out, rmsum, ws);
  fin_k<<<1, 1, 0, stream>>>(ws, out);
}

// Round 10
// 509.268 us; speedup vs baseline: 2.3024x; 2.3024x over previous
//
#include <hip/hip_runtime.h>
#include <hip/hip_bf16.h>

// BRITS-style RNN (B=4096, T=256, D=36, H=64) on gfx950.
// R10: R9 schedule with natural register allocation (__launch_bounds__(512), no
// wave minimum). R9's (512,4) clamped to 64 VGPR -> spill (WRITE 147->193MB,
// 1172us). Three clamp attempts (R4/R7/R9) all spilled and never gained
// occupancy -> abandon 2-blocks/CU; optimize the 1-block/CU critical path.
// Schedule: gamma(t)/beta(t) are h-independent, so S-waves compute them for t+1
// in P2 (overlapping G's gi-kt2/3+GRU). S-P1 = vx(2 MFMA)->vc1->feat(6)->impute
// (beta in regs)->vc2: ONE LDS round-trip on the h-critical path.
// G-P1 = gh(6, whh from LDS)+gi-kt0/1(6)+staging; G-P2 = gi-kt2/3(6)+GRU.
// S-waves 4-7 own row slices {s,4+s,8+s,12+s} (acc slot q=sW); 2 barriers/step.

#define Bsz 4096
#define Tn  256
#define Dn  36
#define ROWS 16
#define EPSf 1e-5f
#define VMST 38

using f32x4 = __attribute__((ext_vector_type(4))) float;
using s8    = __attribute__((ext_vector_type(8))) short;

__device__ __forceinline__ short f2bf(float x) {
  return (short)__bfloat16_as_ushort(__float2bfloat16(x));
}
__device__ __forceinline__ float sigf(float x) { return 1.f / (1.f + __expf(-x)); }
__device__ __forceinline__ float tanhfast(float x) { return 1.f - 2.f / (1.f + __expf(2.f * x)); }
// fragment-linear offset for element (row, k) of an MFMA A-tile (16 rows, bf16)
__device__ __forceinline__ int fragoff(int row, int k) {
  return ((k >> 5) << 9) + (((k >> 3) & 3) << 7) + (row << 3) + (k & 7);
}
// v[s] for wave-uniform runtime s without scratch
__device__ __forceinline__ float selq(f32x4 v, int s) {
  float a = (s & 1) ? v[1] : v[0];
  float b = (s & 1) ? v[3] : v[2];
  return (s & 2) ? b : a;
}
#define MFMA __builtin_amdgcn_mfma_f32_16x16x32_bf16

// ---------------- prepass: rmsum[t] = 1/(sum(masks[:,t,:]) + EPS) -------------
__global__ void msum_k(const float4* __restrict__ masks4, float* __restrict__ rmsum) {
  int t = blockIdx.x;
  float s = 0.f;
  for (int r = threadIdx.x; r < Bsz; r += 256) {
    const float4* mp = masks4 + ((size_t)r * Tn + t) * 9;
    #pragma unroll
    for (int j = 0; j < 9; ++j) { float4 v = mp[j]; s += v.x + v.y + v.z + v.w; }
  }
  __shared__ float red[256];
  red[threadIdx.x] = s;
  __syncthreads();
  for (int k = 128; k > 0; k >>= 1) {
    if (threadIdx.x < k) red[threadIdx.x] += red[threadIdx.x + k];
    __syncthreads();
  }
  if (threadIdx.x == 0) rmsum[t] = 1.f / (red[0] + EPSf);
}

// ---------------- main ---------------------------------------------------------
__global__ __launch_bounds__(512) void brits_main(
    const float* __restrict__ values, const float* __restrict__ masks,
    const float* __restrict__ deltas, const float* __restrict__ label,
    const float* __restrict__ is_train,
    const float* __restrict__ W_ih, const float* __restrict__ W_hh,
    const float* __restrict__ b_ih, const float* __restrict__ b_hh,
    const float* __restrict__ hist_W, const float* __restrict__ hist_b,
    const float* __restrict__ feat_W, const float* __restrict__ feat_b,
    const float* __restrict__ decay_W, const float* __restrict__ decay_b,
    const float* __restrict__ comb_W, const float* __restrict__ comb_b,
    const float* __restrict__ out_W, const float* __restrict__ out_b,
    float* __restrict__ out, const float* __restrict__ rmsum,
    float* __restrict__ ws_acc /* [0] il, [1] cls, [2] wsum */) {

  __shared__ __align__(16) float2 vm_s[2][ROWS * VMST];  // (value, mask)
  __shared__ __align__(16) short hbuf[1024];        // h bf16, K=64 frag-linear
  __shared__ __align__(16) short dbuf[2][1024];     // delta, parity-buffered
  __shared__ __align__(16) short xbuf[2][2048];     // [mask|gamma|vc2|pad] K=128
  __shared__ __align__(16) short vcbuf[4][1024];    // per-S-wave private vc1
  __shared__ __align__(16) short cxbuf[4][1536];    // per-S-wave [gamma|mask] K=96
  __shared__ __align__(16) short whh_l[24 * 512];   // [gw][g][kt] B-frags, 24KB
  __shared__ __align__(16) short comb_l[9 * 512];   // [t3][kt] B-frags, 9KB
  __shared__ float red16[16];

  const int tid  = threadIdx.x;
  const int w    = tid >> 6;        // wave 0..7
  const int lane = tid & 63;
  const int lc   = lane & 15;
  const int r4   = lane >> 4;
  const int row0 = blockIdx.x * ROWS;
  const int k0b  = r4 * 8;
  const int lw8  = lane * 8;

  const bool isG = (w < 4);
  const int  sW  = isG ? 0 : (w - 4);
  const int  dim = 16 * (isG ? w : 0) + lc;
  const int  myrow = 4 * r4 + sW;

  // ---- role-overlaid VGPR weight fragments ----
  // G: bf[0..11] = wih (xbuf k-space remap), gate g occupies [g*4 .. g*4+3]
  // S: bf[0..5]=dec, bf[6..11]=feat(zero diag), bf[12..13]=hist(all cols)
  s8 bf[14];
  #pragma unroll
  for (int i = 0; i < 14; ++i) bf[i] = (s8)(short)0;

  if (isG) {
    #pragma unroll
    for (int g = 0; g < 3; ++g) {
      const int n = 64 * g + dim;
      #pragma unroll
      for (int kt = 0; kt < 4; ++kt) {
        s8 f;
        #pragma unroll
        for (int e = 0; e < 8; ++e) {
          int xk = k0b + 32 * kt + e;
          // xbuf k-space [mask(0:36)|gamma(36:72)|vc2(72:108)|pad]
          // W_ih cols    [vc(0:36)|mask(36:72)|gamma(72:108)]
          float wv = 0.f;
          if (xk < 72) wv = W_ih[n * 108 + 36 + xk];
          else if (xk < 108) wv = W_ih[n * 108 + xk - 72];
          f[e] = f2bf(wv);
        }
        bf[g * 4 + kt] = f;
      }
      // whh -> LDS (consumed in G-P1)
      #pragma unroll
      for (int kt = 0; kt < 2; ++kt) {
        s8 f;
        #pragma unroll
        for (int e = 0; e < 8; ++e) f[e] = f2bf(W_hh[n * 64 + k0b + 32 * kt + e]);
        *(s8*)&whh_l[(w * 6 + g * 2 + kt) * 512 + lw8] = f;
      }
    }
  } else {
    #pragma unroll
    for (int t3 = 0; t3 < 3; ++t3) {
      const int col = 16 * t3 + lc;
      const bool cok = (col < Dn);
      #pragma unroll
      for (int kt = 0; kt < 2; ++kt) {
        s8 fd, ff;
        #pragma unroll
        for (int e = 0; e < 8; ++e) {
          int k = k0b + 32 * kt + e;
          fd[e] = f2bf((cok && k < Dn) ? decay_W[col * Dn + k] : 0.f);
          ff[e] = f2bf((cok && k < Dn && k != col) ? feat_W[col * Dn + k] : 0.f);
        }
        bf[t3 * 2 + kt] = fd;
        bf[6 + t3 * 2 + kt] = ff;
      }
    }
    #pragma unroll
    for (int kt = 0; kt < 2; ++kt) {
      s8 f;
      #pragma unroll
      for (int e = 0; e < 8; ++e) f[e] = f2bf(hist_W[k0b + 32 * kt + e]);
      bf[12 + kt] = f;
    }
    if (w == 4) {   // comb B-frags are wave-invariant -> one writer
      #pragma unroll
      for (int t3 = 0; t3 < 3; ++t3) {
        const int col = 16 * t3 + lc;
        const bool cok = (col < Dn);
        #pragma unroll
        for (int kt = 0; kt < 3; ++kt) {
          s8 f;
          #pragma unroll
          for (int e = 0; e < 8; ++e) {
            int k = k0b + 32 * kt + e;  // cxbuf k-space [gamma(0:36)|mask(36:72)]
            f[e] = f2bf((cok && k < 72) ? comb_W[col * 72 + k] : 0.f);
          }
          *(s8*)&comb_l[(t3 * 3 + kt) * 512 + lw8] = f;
        }
      }
    }
  }

  // per-lane constants
  float db3[3] = {0,0,0}, fb3[3] = {0,0,0}, cb3[3] = {0,0,0};
  float br = 0.f, bz = 0.f, bin_ = 0.f, bhn = 0.f, ow = 0.f;
  if (isG) {
    br   = b_ih[dim] + b_hh[dim];
    bz   = b_ih[64 + dim] + b_hh[64 + dim];
    bin_ = b_ih[128 + dim];
    bhn  = b_hh[128 + dim];
    ow   = out_W[dim];
  } else {
    #pragma unroll
    for (int t3 = 0; t3 < 3; ++t3) {
      int col = 16 * t3 + lc;
      if (col < Dn) { db3[t3] = decay_b[col]; fb3[t3] = feat_b[col]; cb3[t3] = comb_b[col]; }
    }
  }
  const float histb = hist_b[0];
  const int hb = fragoff(0, dim);

  // staging geometry (G waves, tids 0..143): 16 rows x 9 quads
  const bool stg = (tid < 144);
  const int srow = tid / 9;
  const int squad = tid - srow * 9;
  const size_t sbase = ((size_t)(row0 + srow) * Tn) * Dn + squad * 4;
  const int sfo = fragoff(srow, squad * 4);
  const int svo = srow * VMST + squad * 4;

  // S mask->cxbuf geometry (lane < 36)
  const int mrow = 4 * (lane / 9) + sW;
  const int mc0  = (lane % 9) * 4;

  // ---- init LDS ----
  for (int i = tid; i < 1024; i += 512) {
    hbuf[i] = 0; dbuf[0][i] = 0; dbuf[1][i] = 0;
    vcbuf[0][i] = 0; vcbuf[1][i] = 0; vcbuf[2][i] = 0; vcbuf[3][i] = 0;
  }
  for (int i = tid; i < 2048; i += 512) { xbuf[0][i] = 0; xbuf[1][i] = 0; }
  for (int i = tid; i < 1536; i += 512) {
    cxbuf[0][i] = 0; cxbuf[1][i] = 0; cxbuf[2][i] = 0; cxbuf[3][i] = 0;
  }
  __syncthreads();

  // ---- prologue: stage t=0 (parity 0), prefetch t=1 ----
  float4 pv = {0,0,0,0}, pm = {0,0,0,0}, pd = {0,0,0,0};
  if (stg) {
    float4 v0 = *(const float4*)&values[sbase];
    float4 m0 = *(const float4*)&masks[sbase];
    float4 d0 = *(const float4*)&deltas[sbase];
    *(float4*)&vm_s[0][svo]     = make_float4(v0.x, m0.x, v0.y, m0.y);
    *(float4*)&vm_s[0][svo + 2] = make_float4(v0.z, m0.z, v0.w, m0.w);
    union { short s[4]; uint2 u; } td, tm;
    td.s[0]=f2bf(d0.x); td.s[1]=f2bf(d0.y); td.s[2]=f2bf(d0.z); td.s[3]=f2bf(d0.w);
    tm.s[0]=f2bf(m0.x); tm.s[1]=f2bf(m0.y); tm.s[2]=f2bf(m0.z); tm.s[3]=f2bf(m0.w);
    *(uint2*)&dbuf[0][sfo] = td.u;
    *(uint2*)&xbuf[0][sfo] = tm.u;
    pv = *(const float4*)&values[sbase + Dn];
    pm = *(const float4*)&masks[sbase + Dn];
    pd = *(const float4*)&deltas[sbase + Dn];
  }
  __syncthreads();

  float bq[3] = {0.f, 0.f, 0.f};    // precomputed beta for the CURRENT step
  // S precompute for t=0: Gm/gamma/comb/beta from dbuf[0], vm_s[0]
  if (!isG) {
    s8 ad0 = *(const s8*)&dbuf[0][lw8];
    s8 ad1 = *(const s8*)&dbuf[0][512 + lw8];
    f32x4 G0 = {0,0,0,0}, G1 = {0,0,0,0}, G2 = {0,0,0,0};
    G0 = MFMA(ad0, bf[0], G0, 0,0,0); G0 = MFMA(ad1, bf[1], G0, 0,0,0);
    G1 = MFMA(ad0, bf[2], G1, 0,0,0); G1 = MFMA(ad1, bf[3], G1, 0,0,0);
    G2 = MFMA(ad0, bf[4], G2, 0,0,0); G2 = MFMA(ad1, bf[5], G2, 0,0,0);
    #pragma unroll
    for (int t3 = 0; t3 < 3; ++t3) {
      int col = 16 * t3 + lc;
      if (col < Dn) {
        float gm = (t3==0) ? selq(G0,sW) : (t3==1) ? selq(G1,sW) : selq(G2,sW);
        short gbv = f2bf(__expf(-fmaxf(gm + db3[t3], 0.f)));
        xbuf[0][fragoff(myrow, 36 + col)] = gbv;
        cxbuf[sW][fragoff(myrow, col)] = gbv;
      }
    }
    if (lane < 36) {
      #pragma unroll
      for (int j = 0; j < 4; ++j)
        cxbuf[sW][fragoff(mrow, 36 + mc0 + j)] = f2bf(vm_s[0][mrow * VMST + mc0 + j].y);
    }
    s8 ac0 = *(const s8*)&cxbuf[sW][lw8];
    s8 ac1 = *(const s8*)&cxbuf[sW][512 + lw8];
    s8 ac2 = *(const s8*)&cxbuf[sW][1024 + lw8];
    f32x4 B0 = {0,0,0,0}, B1 = {0,0,0,0}, B2 = {0,0,0,0};
    B0 = MFMA(ac0, *(const s8*)&comb_l[0*512+lw8], B0, 0,0,0);
    B0 = MFMA(ac1, *(const s8*)&comb_l[1*512+lw8], B0, 0,0,0);
    B0 = MFMA(ac2, *(const s8*)&comb_l[2*512+lw8], B0, 0,0,0);
    B1 = MFMA(ac0, *(const s8*)&comb_l[3*512+lw8], B1, 0,0,0);
    B1 = MFMA(ac1, *(const s8*)&comb_l[4*512+lw8], B1, 0,0,0);
    B1 = MFMA(ac2, *(const s8*)&comb_l[5*512+lw8], B1, 0,0,0);
    B2 = MFMA(ac0, *(const s8*)&comb_l[6*512+lw8], B2, 0,0,0);
    B2 = MFMA(ac1, *(const s8*)&comb_l[7*512+lw8], B2, 0,0,0);
    B2 = MFMA(ac2, *(const s8*)&comb_l[8*512+lw8], B2, 0,0,0);
    bq[0] = sigf(selq(B0,sW) + cb3[0]);
    bq[1] = sigf(selq(B1,sW) + cb3[1]);
    bq[2] = sigf(selq(B2,sW) + cb3[2]);
  }

  float hreg[4] = {0.f, 0.f, 0.f, 0.f};
  float lacc[4] = {0.f, 0.f, 0.f, 0.f};
  float il = 0.f;
  __syncthreads();

  #pragma unroll 1
  for (int t = 0; t < Tn; ++t) {
    const float srm = rmsum[t];
    const int p = t & 1;
    f32x4 A0 = {0,0,0,0}, A1 = {0,0,0,0}, A2 = {0,0,0,0}, A3 = {0,0,0,0};

    // ================ P1 ================
    if (isG) {
      const int wb = w * 6 * 512;
      s8 ah0 = *(const s8*)&hbuf[lw8];
      s8 ah1 = *(const s8*)&hbuf[512 + lw8];
      A0 = MFMA(ah0, *(const s8*)&whh_l[wb + lw8],        A0, 0,0,0);
      A0 = MFMA(ah1, *(const s8*)&whh_l[wb + 512 + lw8],  A0, 0,0,0);
      A1 = MFMA(ah0, *(const s8*)&whh_l[wb + 1024 + lw8], A1, 0,0,0);
      A1 = MFMA(ah1, *(const s8*)&whh_l[wb + 1536 + lw8], A1, 0,0,0);
      A3 = MFMA(ah0, *(const s8*)&whh_l[wb + 2048 + lw8], A3, 0,0,0);
      A3 = MFMA(ah1, *(const s8*)&whh_l[wb + 2560 + lw8], A3, 0,0,0);
      s8 ax0 = *(const s8*)&xbuf[p][lw8];
      s8 ax1 = *(const s8*)&xbuf[p][512 + lw8];
      A0 = MFMA(ax0, bf[0], A0, 0,0,0); A0 = MFMA(ax1, bf[1], A0, 0,0,0);
      A1 = MFMA(ax0, bf[4], A1, 0,0,0); A1 = MFMA(ax1, bf[5], A1, 0,0,0);
      A2 = MFMA(ax0, bf[8], A2, 0,0,0); A2 = MFMA(ax1, bf[9], A2, 0,0,0);
      // stage t+1 into parity p^1
      if (stg && t + 1 < Tn) {
        *(float4*)&vm_s[p ^ 1][svo]     = make_float4(pv.x, pm.x, pv.y, pm.y);
        *(float4*)&vm_s[p ^ 1][svo + 2] = make_float4(pv.z, pm.z, pv.w, pm.w);
        union { short s[4]; uint2 u; } td, tm;
        td.s[0]=f2bf(pd.x); td.s[1]=f2bf(pd.y); td.s[2]=f2bf(pd.z); td.s[3]=f2bf(pd.w);
        tm.s[0]=f2bf(pm.x); tm.s[1]=f2bf(pm.y); tm.s[2]=f2bf(pm.z); tm.s[3]=f2bf(pm.w);
        *(uint2*)&dbuf[p ^ 1][sfo] = td.u;
        *(uint2*)&xbuf[p ^ 1][sfo] = tm.u;
      }
      if (stg && t + 2 < Tn) {
        size_t o = sbase + (size_t)(t + 2) * Dn;
        pv = *(const float4*)&values[o];
        pm = *(const float4*)&masks[o];
        pd = *(const float4*)&deltas[o];
      }
    } else {
      // ---- S: h-critical chain only (beta already in regs) ----
      s8 ah0 = *(const s8*)&hbuf[lw8];
      s8 ah1 = *(const s8*)&hbuf[512 + lw8];
      f32x4 X = {0,0,0,0};
      X = MFMA(ah0, bf[12], X, 0,0,0);
      X = MFMA(ah1, bf[13], X, 0,0,0);
      const float vx = selq(X, sW) + histb;
      float v3[3], m3[3];
      #pragma unroll
      for (int t3 = 0; t3 < 3; ++t3) {
        int col = 16 * t3 + lc;
        v3[t3] = 0.f; m3[t3] = 0.f;
        if (col < Dn) {
          float2 vm = vm_s[p][myrow * VMST + col];
          v3[t3] = vm.x; m3[t3] = vm.y;
          il += srm * fabsf(vx - vm.x) * vm.y;
          vcbuf[sW][fragoff(myrow, col)] = f2bf(vm.y * vm.x + (1.f - vm.y) * vx);
        }
      }
      s8 av0 = *(const s8*)&vcbuf[sW][lw8];
      s8 av1 = *(const s8*)&vcbuf[sW][512 + lw8];
      f32x4 Z0 = {0,0,0,0}, Z1 = {0,0,0,0}, Z2 = {0,0,0,0};
      Z0 = MFMA(av0, bf[6],  Z0, 0,0,0); Z0 = MFMA(av1, bf[7],  Z0, 0,0,0);
      Z1 = MFMA(av0, bf[8],  Z1, 0,0,0); Z1 = MFMA(av1, bf[9],  Z1, 0,0,0);
      Z2 = MFMA(av0, bf[10], Z2, 0,0,0); Z2 = MFMA(av1, bf[11], Z2, 0,0,0);
      #pragma unroll
      for (int t3 = 0; t3 < 3; ++t3) {
        int col = 16 * t3 + lc;
        if (col < Dn) {
          float vz = ((t3==0) ? selq(Z0,sW) : (t3==1) ? selq(Z1,sW) : selq(Z2,sW)) + fb3[t3];
          il += srm * fabsf(vz - v3[t3]) * m3[t3];
          float vh = vz * bq[t3] + vx * (1.f - bq[t3]);
          il += srm * fabsf(vh - v3[t3]) * m3[t3];
          float vc2 = m3[t3] * v3[t3] + (1.f - m3[t3]) * vh;
          out[1 + ((size_t)(row0 + myrow) * Tn + t) * Dn + col] = vc2;
          xbuf[p][fragoff(myrow, 72 + col)] = f2bf(vc2);
        }
      }
    }
    __syncthreads();  // b1: vc2 + staged t+1 visible

    // ================ P2 ================
    if (isG) {
      s8 ax2 = *(const s8*)&xbuf[p][1024 + lw8];
      s8 ax3 = *(const s8*)&xbuf[p][1536 + lw8];
      A0 = MFMA(ax2, bf[2],  A0, 0,0,0); A0 = MFMA(ax3, bf[3],  A0, 0,0,0);
      A1 = MFMA(ax2, bf[6],  A1, 0,0,0); A1 = MFMA(ax3, bf[7],  A1, 0,0,0);
      A2 = MFMA(ax2, bf[10], A2, 0,0,0); A2 = MFMA(ax3, bf[11], A2, 0,0,0);
      #pragma unroll
      for (int q = 0; q < 4; ++q) {
        float rg = sigf(A0[q] + br);
        float zg = sigf(A1[q] + bz);
        float ng = tanhfast(A2[q] + bin_ + rg * (A3[q] + bhn));
        float hn = (1.f - zg) * ng + zg * hreg[q];
        hreg[q] = hn;
        lacc[q] += hn * ow;
        hbuf[hb + (r4 * 4 + q) * 8] = f2bf(hn);
      }
    } else if (t + 1 < Tn) {
      // ---- S: precompute Gm/gamma/comb/beta for t+1 (h-independent) ----
      s8 ad0 = *(const s8*)&dbuf[p ^ 1][lw8];
      s8 ad1 = *(const s8*)&dbuf[p ^ 1][512 + lw8];
      f32x4 G0 = {0,0,0,0}, G1 = {0,0,0,0}, G2 = {0,0,0,0};
      G0 = MFMA(ad0, bf[0], G0, 0,0,0); G0 = MFMA(ad1, bf[1], G0, 0,0,0);
      G1 = MFMA(ad0, bf[2], G1, 0,0,0); G1 = MFMA(ad1, bf[3], G1, 0,0,0);
      G2 = MFMA(ad0, bf[4], G2, 0,0,0); G2 = MFMA(ad1, bf[5], G2, 0,0,0);
      #pragma unroll
      for (int t3 = 0; t3 < 3; ++t3) {
        int col = 16 * t3 + lc;
        if (col < Dn) {
          float gm = (t3==0) ? selq(G0,sW) : (t3==1) ? selq(G1,sW) : selq(G2,sW);
          short gbv = f2bf(__expf(-fmaxf(gm + db3[t3], 0.f)));
          xbuf[p ^ 1][fragoff(myrow, 36 + col)] = gbv;
          cxbuf[sW][fragoff(myrow, col)] = gbv;
        }
      }
      if (lane < 36) {
        #pragma unroll
        for (int j = 0; j < 4; ++j)
          cxbuf[sW][fragoff(mrow, 36 + mc0 + j)] =
              f2bf(vm_s[p ^ 1][mrow * VMST + mc0 + j].y);
      }
      s8 ac0 = *(const s8*)&cxbuf[sW][lw8];
      s8 ac1 = *(const s8*)&cxbuf[sW][512 + lw8];
      s8 ac2 = *(const s8*)&cxbuf[sW][1024 + lw8];
      f32x4 B0 = {0,0,0,0}, B1 = {0,0,0,0}, B2 = {0,0,0,0};
      B0 = MFMA(ac0, *(const s8*)&comb_l[0*512+lw8], B0, 0,0,0);
      B0 = MFMA(ac1, *(const s8*)&comb_l[1*512+lw8], B0, 0,0,0);
      B0 = MFMA(ac2, *(const s8*)&comb_l[2*512+lw8], B0, 0,0,0);
      B1 = MFMA(ac0, *(const s8*)&comb_l[3*512+lw8], B1, 0,0,0);
      B1 = MFMA(ac1, *(const s8*)&comb_l[4*512+lw8], B1, 0,0,0);
      B1 = MFMA(ac2, *(const s8*)&comb_l[5*512+lw8], B1, 0,0,0);
      B2 = MFMA(ac0, *(const s8*)&comb_l[6*512+lw8], B2, 0,0,0);
      B2 = MFMA(ac1, *(const s8*)&comb_l[7*512+lw8], B2, 0,0,0);
      B2 = MFMA(ac2, *(const s8*)&comb_l[8*512+lw8], B2, 0,0,0);
      bq[0] = sigf(selq(B0,sW) + cb3[0]);
      bq[1] = sigf(selq(B1,sW) + cb3[1]);
      bq[2] = sigf(selq(B2,sW) + cb3[2]);
    }
    __syncthreads();  // b2: h(t) + gamma(t+1) visible
  }

  // ---- epilogue: reduce il, logits, pred, class loss ----
  float* red_s = (float*)whh_l;   // whh_l dead after the loop
  red_s[tid] = il;
  __syncthreads();
  for (int k = 256; k > 0; k >>= 1) {
    if (tid < k) red_s[tid] += red_s[tid + k];
    __syncthreads();
  }
  if (tid == 0) atomicAdd(&ws_acc[0], red_s[0]);
  if (tid < 16) red16[tid] = 0.f;
  __syncthreads();
  if (isG) {
    #pragma unroll
    for (int q = 0; q < 4; ++q) atomicAdd(&red16[r4 * 4 + q], lacc[q]);
  }
  __syncthreads();

  if (tid < ROWS) {
    float lg = red16[tid] / (float)Tn + out_b[0];
    int rg = row0 + tid;
    float pred = sigf(lg);
    out[1 + (size_t)Bsz * Tn * Dn + rg] = pred;
    float y = label[rg], wt = is_train[rg];
    float bce = fmaxf(lg, 0.f) - lg * y + log1pf(__expf(-fabsf(lg)));
    atomicAdd(&ws_acc[1], bce * wt);
    atomicAdd(&ws_acc[2], wt);
  }
}

// ---------------- finalize loss -------------------------------------------------
__global__ void fin_k(const float* __restrict__ ws, float* __restrict__ out) {
  out[0] = ws[1] / (ws[2] + EPSf) + ws[0] / (float)Tn;
}

extern "C" void kernel_launch(void* const* d_in, const int* in_sizes, int n_in,
                              void* d_out, int out_size, void* d_ws, size_t ws_size,
                              hipStream_t stream) {
  const float* values   = (const float*)d_in[0];
  const float* masks    = (const float*)d_in[1];
  const float* deltas   = (const float*)d_in[2];
  const float* label    = (const float*)d_in[3];
  const float* is_train = (const float*)d_in[4];
  const float* W_ih     = (const float*)d_in[5];
  const float* W_hh     = (const float*)d_in[6];
  const float* b_ih     = (const float*)d_in[7];
  const float* b_hh     = (const float*)d_in[8];
  const float* hist_W   = (const float*)d_in[9];
  const float* hist_b   = (const float*)d_in[10];
  const float* feat_W   = (const float*)d_in[11];
  const float* feat_b   = (const float*)d_in[12];
  const float* decay_W  = (const float*)d_in[13];
  const float* decay_b  = (const float*)d_in[14];
  const float* comb_W   = (const float*)d_in[15];
  const float* comb_b   = (const float*)d_in[16];
  const float* out_W    = (const float*)d_in[17];
  const float* out_b    = (const float*)d_in[18];

  float* ws = (float*)d_ws;
  float* rmsum = ws + 4;
  float* out = (float*)d_out;

  hipMemsetAsync(d_ws, 0, 16, stream);
  msum_k<<<Tn, 256, 0, stream>>>((const float4*)masks, rmsum);
  brits_main<<<Bsz / ROWS, 512, 0, stream>>>(
      values, masks, deltas, label, is_train, W_ih, W_hh, b_ih, b_hh,
      hist_W, hist_b, feat_W, feat_b, decay_W, decay_b, comb_W, comb_b,
      out_W, out_b, out, rmsum, ws);
  fin_k<<<1, 1, 0, stream>>>(ws, out);
}

// Round 11
// 458.321 us; speedup vs baseline: 2.5584x; 1.1112x over previous
//
#include <hip/hip_runtime.h>
#include <hip/hip_bf16.h>

// BRITS-style RNN (B=4096, T=256, D=36, H=64) on gfx950.
// R11: hybrid of R8 (all weights in VGPRs - 447us) and R10's schedule (gamma/
// comb/beta for t+1 computed in S-P2, h-independent), plus:
//  - cxbuf ELIMINATED: comb reads xbuf directly with weights remapped to xbuf
//    k-space ([mask(0:36)|gamma(36:72)|vc2-stale x 0]) - saves 7 scattered LDS
//    writes per S-wave-step and one buffer.
//  - #pragma unroll 2 on the t-loop: parity folds per clone -> LDS base
//    addresses loop-invariant (cuts address VALU; VALUBusy was ~50%).
// Roles: G-waves 0-3 (gate dims 16w+lc): P1 gh(6)+gi-kt0/1(6)+staging t+1;
// P2 gi-kt2/3(6)+GRU+hbuf. S-waves 4-7 (row slice {s,4+s,8+s,12+s}, acc q=sW):
// P1 vx(2)->vc1->feat(6)->impute(beta in regs)->vc2; P2 Gm(6)+gamma+comb(9)
// +beta for t+1. 2 barriers/step. 1 block/CU (8 waves); no launch_bounds min
// (R4/R7/R9: clamps spill).

#define Bsz 4096
#define Tn  256
#define Dn  36
#define ROWS 16
#define EPSf 1e-5f
#define VMST 38

using f32x4 = __attribute__((ext_vector_type(4))) float;
using s8    = __attribute__((ext_vector_type(8))) short;

__device__ __forceinline__ short f2bf(float x) {
  return (short)__bfloat16_as_ushort(__float2bfloat16(x));
}
__device__ __forceinline__ float sigf(float x) { return 1.f / (1.f + __expf(-x)); }
__device__ __forceinline__ float tanhfast(float x) { return 1.f - 2.f / (1.f + __expf(2.f * x)); }
// fragment-linear offset for element (row, k) of an MFMA A-tile (16 rows, bf16)
__device__ __forceinline__ int fragoff(int row, int k) {
  return ((k >> 5) << 9) + (((k >> 3) & 3) << 7) + (row << 3) + (k & 7);
}
// v[s] for wave-uniform runtime s without scratch
__device__ __forceinline__ float selq(f32x4 v, int s) {
  float a = (s & 1) ? v[1] : v[0];
  float b = (s & 1) ? v[3] : v[2];
  return (s & 2) ? b : a;
}
#define MFMA __builtin_amdgcn_mfma_f32_16x16x32_bf16

// ---------------- prepass: rmsum[t] = 1/(sum(masks[:,t,:]) + EPS) -------------
__global__ void msum_k(const float4* __restrict__ masks4, float* __restrict__ rmsum) {
  int t = blockIdx.x;
  float s = 0.f;
  for (int r = threadIdx.x; r < Bsz; r += 256) {
    const float4* mp = masks4 + ((size_t)r * Tn + t) * 9;
    #pragma unroll
    for (int j = 0; j < 9; ++j) { float4 v = mp[j]; s += v.x + v.y + v.z + v.w; }
  }
  __shared__ float red[256];
  red[threadIdx.x] = s;
  __syncthreads();
  for (int k = 128; k > 0; k >>= 1) {
    if (threadIdx.x < k) red[threadIdx.x] += red[threadIdx.x + k];
    __syncthreads();
  }
  if (threadIdx.x == 0) rmsum[t] = 1.f / (red[0] + EPSf);
}

// ---------------- main ---------------------------------------------------------
__global__ __launch_bounds__(512) void brits_main(
    const float* __restrict__ values, const float* __restrict__ masks,
    const float* __restrict__ deltas, const float* __restrict__ label,
    const float* __restrict__ is_train,
    const float* __restrict__ W_ih, const float* __restrict__ W_hh,
    const float* __restrict__ b_ih, const float* __restrict__ b_hh,
    const float* __restrict__ hist_W, const float* __restrict__ hist_b,
    const float* __restrict__ feat_W, const float* __restrict__ feat_b,
    const float* __restrict__ decay_W, const float* __restrict__ decay_b,
    const float* __restrict__ comb_W, const float* __restrict__ comb_b,
    const float* __restrict__ out_W, const float* __restrict__ out_b,
    float* __restrict__ out, const float* __restrict__ rmsum,
    float* __restrict__ ws_acc /* [0] il, [1] cls, [2] wsum */) {

  __shared__ __align__(16) float2 vm_s[2][ROWS * VMST];  // (value, mask)
  __shared__ __align__(16) short hbuf[1024];        // h bf16, K=64 frag-linear
  __shared__ __align__(16) short dbuf[2][1024];     // delta, parity-buffered
  __shared__ __align__(16) short xbuf[2][2048];     // [mask|gamma|vc2|pad] K=128
  __shared__ __align__(16) short vcbuf[4][1024];    // per-S-wave private vc1
  __shared__ float red_s[512];
  __shared__ float red16[16];

  const int tid  = threadIdx.x;
  const int w    = tid >> 6;        // wave 0..7
  const int lane = tid & 63;
  const int lc   = lane & 15;
  const int r4   = lane >> 4;
  const int row0 = blockIdx.x * ROWS;
  const int k0b  = r4 * 8;
  const int lw8  = lane * 8;

  const bool isG = (w < 4);
  const int  sW  = isG ? 0 : (w - 4);
  const int  dim = 16 * (isG ? w : 0) + lc;
  const int  myrow = 4 * r4 + sW;

  // ---- role-overlaid VGPR weight fragments ----
  // G: bf[0..11] = wih (xbuf k-space remap), bf[12..17] = whh
  // S: bf[0..5]=dec, bf[6..11]=feat(zero diag), bf[12..13]=hist(all cols),
  //    bf[14..22]=comb REMAPPED to xbuf k-space (mask part<->gamma part)
  s8 bf[23];
  #pragma unroll
  for (int i = 0; i < 23; ++i) bf[i] = (s8)(short)0;

  if (isG) {
    #pragma unroll
    for (int g = 0; g < 3; ++g) {
      const int n = 64 * g + dim;
      #pragma unroll
      for (int kt = 0; kt < 4; ++kt) {
        s8 f;
        #pragma unroll
        for (int e = 0; e < 8; ++e) {
          int xk = k0b + 32 * kt + e;
          // xbuf k-space [mask(0:36)|gamma(36:72)|vc2(72:108)|pad]
          // W_ih cols    [vc(0:36)|mask(36:72)|gamma(72:108)]
          float wv = 0.f;
          if (xk < 72) wv = W_ih[n * 108 + 36 + xk];
          else if (xk < 108) wv = W_ih[n * 108 + xk - 72];
          f[e] = f2bf(wv);
        }
        bf[g * 4 + kt] = f;
      }
      #pragma unroll
      for (int kt = 0; kt < 2; ++kt) {
        s8 f;
        #pragma unroll
        for (int e = 0; e < 8; ++e) f[e] = f2bf(W_hh[n * 64 + k0b + 32 * kt + e]);
        bf[12 + g * 2 + kt] = f;
      }
    }
  } else {
    #pragma unroll
    for (int t3 = 0; t3 < 3; ++t3) {
      const int col = 16 * t3 + lc;
      const bool cok = (col < Dn);
      #pragma unroll
      for (int kt = 0; kt < 2; ++kt) {
        s8 fd, ff;
        #pragma unroll
        for (int e = 0; e < 8; ++e) {
          int k = k0b + 32 * kt + e;
          fd[e] = f2bf((cok && k < Dn) ? decay_W[col * Dn + k] : 0.f);
          ff[e] = f2bf((cok && k < Dn && k != col) ? feat_W[col * Dn + k] : 0.f);
        }
        bf[t3 * 2 + kt] = fd;
        bf[6 + t3 * 2 + kt] = ff;
      }
      // comb remapped: xbuf k<36 = mask -> comb_W[.,36+k]; 36<=k<72 = gamma ->
      // comb_W[.,k-36]; k>=72 (stale vc2 / pad) -> 0
      #pragma unroll
      for (int kt = 0; kt < 3; ++kt) {
        s8 f;
        #pragma unroll
        for (int e = 0; e < 8; ++e) {
          int xk = k0b + 32 * kt + e;
          float wv = 0.f;
          if (cok) {
            if (xk < 36) wv = comb_W[col * 72 + 36 + xk];
            else if (xk < 72) wv = comb_W[col * 72 + xk - 36];
          }
          f[e] = f2bf(wv);
        }
        bf[14 + t3 * 3 + kt] = f;
      }
    }
    #pragma unroll
    for (int kt = 0; kt < 2; ++kt) {
      s8 f;
      #pragma unroll
      for (int e = 0; e < 8; ++e) f[e] = f2bf(hist_W[k0b + 32 * kt + e]);
      bf[12 + kt] = f;
    }
  }

  // per-lane constants
  float db3[3] = {0,0,0}, fb3[3] = {0,0,0}, cb3[3] = {0,0,0};
  float br = 0.f, bz = 0.f, bin_ = 0.f, bhn = 0.f, ow = 0.f;
  if (isG) {
    br   = b_ih[dim] + b_hh[dim];
    bz   = b_ih[64 + dim] + b_hh[64 + dim];
    bin_ = b_ih[128 + dim];
    bhn  = b_hh[128 + dim];
    ow   = out_W[dim];
  } else {
    #pragma unroll
    for (int t3 = 0; t3 < 3; ++t3) {
      int col = 16 * t3 + lc;
      if (col < Dn) { db3[t3] = decay_b[col]; fb3[t3] = feat_b[col]; cb3[t3] = comb_b[col]; }
    }
  }
  const float histb = hist_b[0];
  const int hb = fragoff(0, dim);

  // staging geometry (G waves, tids 0..143): 16 rows x 9 quads
  const bool stg = (tid < 144);
  const int srow = tid / 9;
  const int squad = tid - srow * 9;
  const size_t sbase = ((size_t)(row0 + srow) * Tn) * Dn + squad * 4;
  const int sfo = fragoff(srow, squad * 4);
  const int svo = srow * VMST + squad * 4;

  // ---- init LDS ----
  for (int i = tid; i < 1024; i += 512) {
    hbuf[i] = 0; dbuf[0][i] = 0; dbuf[1][i] = 0;
    vcbuf[0][i] = 0; vcbuf[1][i] = 0; vcbuf[2][i] = 0; vcbuf[3][i] = 0;
  }
  for (int i = tid; i < 2048; i += 512) { xbuf[0][i] = 0; xbuf[1][i] = 0; }
  __syncthreads();

  // ---- prologue: stage t=0 (parity 0), prefetch t=1 ----
  float4 pv = {0,0,0,0}, pm = {0,0,0,0}, pd = {0,0,0,0};
  if (stg) {
    float4 v0 = *(const float4*)&values[sbase];
    float4 m0 = *(const float4*)&masks[sbase];
    float4 d0 = *(const float4*)&deltas[sbase];
    *(float4*)&vm_s[0][svo]     = make_float4(v0.x, m0.x, v0.y, m0.y);
    *(float4*)&vm_s[0][svo + 2] = make_float4(v0.z, m0.z, v0.w, m0.w);
    union { short s[4]; uint2 u; } td, tm;
    td.s[0]=f2bf(d0.x); td.s[1]=f2bf(d0.y); td.s[2]=f2bf(d0.z); td.s[3]=f2bf(d0.w);
    tm.s[0]=f2bf(m0.x); tm.s[1]=f2bf(m0.y); tm.s[2]=f2bf(m0.z); tm.s[3]=f2bf(m0.w);
    *(uint2*)&dbuf[0][sfo] = td.u;
    *(uint2*)&xbuf[0][sfo] = tm.u;
    pv = *(const float4*)&values[sbase + Dn];
    pm = *(const float4*)&masks[sbase + Dn];
    pd = *(const float4*)&deltas[sbase + Dn];
  }
  __syncthreads();

  float bq[3] = {0.f, 0.f, 0.f};    // precomputed beta for the CURRENT step
  // S prologue for t=0: Gm/gamma -> xbuf[0]; comb reads xbuf[0] (vc2 region
  // zero-init x zero weight = benign); beta(0) -> bq
  if (!isG) {
    s8 ad0 = *(const s8*)&dbuf[0][lw8];
    s8 ad1 = *(const s8*)&dbuf[0][512 + lw8];
    f32x4 G0 = {0,0,0,0}, G1 = {0,0,0,0}, G2 = {0,0,0,0};
    G0 = MFMA(ad0, bf[0], G0, 0,0,0); G0 = MFMA(ad1, bf[1], G0, 0,0,0);
    G1 = MFMA(ad0, bf[2], G1, 0,0,0); G1 = MFMA(ad1, bf[3], G1, 0,0,0);
    G2 = MFMA(ad0, bf[4], G2, 0,0,0); G2 = MFMA(ad1, bf[5], G2, 0,0,0);
    #pragma unroll
    for (int t3 = 0; t3 < 3; ++t3) {
      int col = 16 * t3 + lc;
      if (col < Dn) {
        float gm = (t3==0) ? selq(G0,sW) : (t3==1) ? selq(G1,sW) : selq(G2,sW);
        xbuf[0][fragoff(myrow, 36 + col)] = f2bf(__expf(-fmaxf(gm + db3[t3], 0.f)));
      }
    }
    s8 ac0 = *(const s8*)&xbuf[0][lw8];
    s8 ac1 = *(const s8*)&xbuf[0][512 + lw8];
    s8 ac2 = *(const s8*)&xbuf[0][1024 + lw8];
    f32x4 B0 = {0,0,0,0}, B1 = {0,0,0,0}, B2 = {0,0,0,0};
    B0 = MFMA(ac0, bf[14], B0, 0,0,0); B0 = MFMA(ac1, bf[15], B0, 0,0,0);
    B0 = MFMA(ac2, bf[16], B0, 0,0,0);
    B1 = MFMA(ac0, bf[17], B1, 0,0,0); B1 = MFMA(ac1, bf[18], B1, 0,0,0);
    B1 = MFMA(ac2, bf[19], B1, 0,0,0);
    B2 = MFMA(ac0, bf[20], B2, 0,0,0); B2 = MFMA(ac1, bf[21], B2, 0,0,0);
    B2 = MFMA(ac2, bf[22], B2, 0,0,0);
    bq[0] = sigf(selq(B0,sW) + cb3[0]);
    bq[1] = sigf(selq(B1,sW) + cb3[1]);
    bq[2] = sigf(selq(B2,sW) + cb3[2]);
  }

  float hreg[4] = {0.f, 0.f, 0.f, 0.f};
  float lacc[4] = {0.f, 0.f, 0.f, 0.f};
  float il = 0.f;
  __syncthreads();

  #pragma unroll 2
  for (int t = 0; t < Tn; ++t) {
    const float srm = rmsum[t];
    const int p = t & 1;                 // folds per unrolled clone
    short* __restrict__ xb  = xbuf[p];
    short* __restrict__ xb2 = xbuf[p ^ 1];
    short* __restrict__ db2 = dbuf[p ^ 1];
    f32x4 A0 = {0,0,0,0}, A1 = {0,0,0,0}, A2 = {0,0,0,0}, A3 = {0,0,0,0};

    // ================ P1 ================
    if (isG) {
      s8 ah0 = *(const s8*)&hbuf[lw8];
      s8 ah1 = *(const s8*)&hbuf[512 + lw8];
      A0 = MFMA(ah0, bf[12], A0, 0,0,0); A0 = MFMA(ah1, bf[13], A0, 0,0,0);
      A1 = MFMA(ah0, bf[14], A1, 0,0,0); A1 = MFMA(ah1, bf[15], A1, 0,0,0);
      A3 = MFMA(ah0, bf[16], A3, 0,0,0); A3 = MFMA(ah1, bf[17], A3, 0,0,0);
      s8 ax0 = *(const s8*)&xb[lw8];
      s8 ax1 = *(const s8*)&xb[512 + lw8];
      A0 = MFMA(ax0, bf[0], A0, 0,0,0); A0 = MFMA(ax1, bf[1], A0, 0,0,0);
      A1 = MFMA(ax0, bf[4], A1, 0,0,0); A1 = MFMA(ax1, bf[5], A1, 0,0,0);
      A2 = MFMA(ax0, bf[8], A2, 0,0,0); A2 = MFMA(ax1, bf[9], A2, 0,0,0);
      // stage t+1 into parity p^1
      if (stg && t + 1 < Tn) {
        *(float4*)&vm_s[p ^ 1][svo]     = make_float4(pv.x, pm.x, pv.y, pm.y);
        *(float4*)&vm_s[p ^ 1][svo + 2] = make_float4(pv.z, pm.z, pv.w, pm.w);
        union { short s[4]; uint2 u; } td, tm;
        td.s[0]=f2bf(pd.x); td.s[1]=f2bf(pd.y); td.s[2]=f2bf(pd.z); td.s[3]=f2bf(pd.w);
        tm.s[0]=f2bf(pm.x); tm.s[1]=f2bf(pm.y); tm.s[2]=f2bf(pm.z); tm.s[3]=f2bf(pm.w);
        *(uint2*)&db2[sfo] = td.u;
        *(uint2*)&xb2[sfo] = tm.u;
      }
      if (stg && t + 2 < Tn) {
        size_t o = sbase + (size_t)(t + 2) * Dn;
        pv = *(const float4*)&values[o];
        pm = *(const float4*)&masks[o];
        pd = *(const float4*)&deltas[o];
      }
    } else {
      // ---- S: h-critical chain only (beta already in regs) ----
      s8 ah0 = *(const s8*)&hbuf[lw8];
      s8 ah1 = *(const s8*)&hbuf[512 + lw8];
      f32x4 X = {0,0,0,0};
      X = MFMA(ah0, bf[12], X, 0,0,0);
      X = MFMA(ah1, bf[13], X, 0,0,0);
      const float vx = selq(X, sW) + histb;
      float v3[3], m3[3];
      #pragma unroll
      for (int t3 = 0; t3 < 3; ++t3) {
        int col = 16 * t3 + lc;
        v3[t3] = 0.f; m3[t3] = 0.f;
        if (col < Dn) {
          float2 vm = vm_s[p][myrow * VMST + col];
          v3[t3] = vm.x; m3[t3] = vm.y;
          il += srm * fabsf(vx - vm.x) * vm.y;
          vcbuf[sW][fragoff(myrow, col)] = f2bf(vm.y * vm.x + (1.f - vm.y) * vx);
        }
      }
      s8 av0 = *(const s8*)&vcbuf[sW][lw8];
      s8 av1 = *(const s8*)&vcbuf[sW][512 + lw8];
      f32x4 Z0 = {0,0,0,0}, Z1 = {0,0,0,0}, Z2 = {0,0,0,0};
      Z0 = MFMA(av0, bf[6],  Z0, 0,0,0); Z0 = MFMA(av1, bf[7],  Z0, 0,0,0);
      Z1 = MFMA(av0, bf[8],  Z1, 0,0,0); Z1 = MFMA(av1, bf[9],  Z1, 0,0,0);
      Z2 = MFMA(av0, bf[10], Z2, 0,0,0); Z2 = MFMA(av1, bf[11], Z2, 0,0,0);
      #pragma unroll
      for (int t3 = 0; t3 < 3; ++t3) {
        int col = 16 * t3 + lc;
        if (col < Dn) {
          float vz = ((t3==0) ? selq(Z0,sW) : (t3==1) ? selq(Z1,sW) : selq(Z2,sW)) + fb3[t3];
          il += srm * fabsf(vz - v3[t3]) * m3[t3];
          float vh = vz * bq[t3] + vx * (1.f - bq[t3]);
          il += srm * fabsf(vh - v3[t3]) * m3[t3];
          float vc2 = m3[t3] * v3[t3] + (1.f - m3[t3]) * vh;
          out[1 + ((size_t)(row0 + myrow) * Tn + t) * Dn + col] = vc2;
          xb[fragoff(myrow, 72 + col)] = f2bf(vc2);
        }
      }
    }
    __syncthreads();  // b1: vc2 + staged t+1 visible

    // ================ P2 ================
    if (isG) {
      s8 ax2 = *(const s8*)&xb[1024 + lw8];
      s8 ax3 = *(const s8*)&xb[1536 + lw8];
      A0 = MFMA(ax2, bf[2],  A0, 0,0,0); A0 = MFMA(ax3, bf[3],  A0, 0,0,0);
      A1 = MFMA(ax2, bf[6],  A1, 0,0,0); A1 = MFMA(ax3, bf[7],  A1, 0,0,0);
      A2 = MFMA(ax2, bf[10], A2, 0,0,0); A2 = MFMA(ax3, bf[11], A2, 0,0,0);
      #pragma unroll
      for (int q = 0; q < 4; ++q) {
        float rg = sigf(A0[q] + br);
        float zg = sigf(A1[q] + bz);
        float ng = tanhfast(A2[q] + bin_ + rg * (A3[q] + bhn));
        float hn = (1.f - zg) * ng + zg * hreg[q];
        hreg[q] = hn;
        lacc[q] += hn * ow;
        hbuf[hb + (r4 * 4 + q) * 8] = f2bf(hn);
      }
    } else if (t + 1 < Tn) {
      // ---- S: precompute Gm/gamma/comb/beta for t+1 (h-independent) ----
      s8 ad0 = *(const s8*)&db2[lw8];
      s8 ad1 = *(const s8*)&db2[512 + lw8];
      f32x4 G0 = {0,0,0,0}, G1 = {0,0,0,0}, G2 = {0,0,0,0};
      G0 = MFMA(ad0, bf[0], G0, 0,0,0); G0 = MFMA(ad1, bf[1], G0, 0,0,0);
      G1 = MFMA(ad0, bf[2], G1, 0,0,0); G1 = MFMA(ad1, bf[3], G1, 0,0,0);
      G2 = MFMA(ad0, bf[4], G2, 0,0,0); G2 = MFMA(ad1, bf[5], G2, 0,0,0);
      #pragma unroll
      for (int t3 = 0; t3 < 3; ++t3) {
        int col = 16 * t3 + lc;
        if (col < Dn) {
          float gm = (t3==0) ? selq(G0,sW) : (t3==1) ? selq(G1,sW) : selq(G2,sW);
          xb2[fragoff(myrow, 36 + col)] = f2bf(__expf(-fmaxf(gm + db3[t3], 0.f)));
        }
      }
      // comb reads xbuf[p^1]: mask (staged this step), gamma (just written,
      // same-wave lgkmcnt), vc2 region stale x zero weight = benign
      s8 ac0 = *(const s8*)&xb2[lw8];
      s8 ac1 = *(const s8*)&xb2[512 + lw8];
      s8 ac2 = *(const s8*)&xb2[1024 + lw8];
      f32x4 B0 = {0,0,0,0}, B1 = {0,0,0,0}, B2 = {0,0,0,0};
      B0 = MFMA(ac0, bf[14], B0, 0,0,0); B0 = MFMA(ac1, bf[15], B0, 0,0,0);
      B0 = MFMA(ac2, bf[16], B0, 0,0,0);
      B1 = MFMA(ac0, bf[17], B1, 0,0,0); B1 = MFMA(ac1, bf[18], B1, 0,0,0);
      B1 = MFMA(ac2, bf[19], B1, 0,0,0);
      B2 = MFMA(ac0, bf[20], B2, 0,0,0); B2 = MFMA(ac1, bf[21], B2, 0,0,0);
      B2 = MFMA(ac2, bf[22], B2, 0,0,0);
      bq[0] = sigf(selq(B0,sW) + cb3[0]);
      bq[1] = sigf(selq(B1,sW) + cb3[1]);
      bq[2] = sigf(selq(B2,sW) + cb3[2]);
    }
    __syncthreads();  // b2: h(t) + gamma(t+1) visible
  }

  // ---- epilogue: reduce il, logits, pred, class loss ----
  red_s[tid] = il;
  __syncthreads();
  for (int k = 256; k > 0; k >>= 1) {
    if (tid < k) red_s[tid] += red_s[tid + k];
    __syncthreads();
  }
  if (tid == 0) atomicAdd(&ws_acc[0], red_s[0]);
  if (tid < 16) red16[tid] = 0.f;
  __syncthreads();
  if (isG) {
    #pragma unroll
    for (int q = 0; q < 4; ++q) atomicAdd(&red16[r4 * 4 + q], lacc[q]);
  }
  __syncthreads();

  if (tid < ROWS) {
    float lg = red16[tid] / (float)Tn + out_b[0];
    int rg = row0 + tid;
    float pred = sigf(lg);
    out[1 + (size_t)Bsz * Tn * Dn + rg] = pred;
    float y = label[rg], wt = is_train[rg];
    float bce = fmaxf(lg, 0.f) - lg * y + log1pf(__expf(-fabsf(lg)));
    atomicAdd(&ws_acc[1], bce * wt);
    atomicAdd(&ws_acc[2], wt);
  }
}

// ---------------- finalize loss -------------------------------------------------
__global__ void fin_k(const float* __restrict__ ws, float* __restrict__ out) {
  out[0] = ws[1] / (ws[2] + EPSf) + ws[0] / (float)Tn;
}

extern "C" void kernel_launch(void* const* d_in, const int* in_sizes, int n_in,
                              void* d_out, int out_size, void* d_ws, size_t ws_size,
                              hipStream_t stream) {
  const float* values   = (const float*)d_in[0];
  const float* masks    = (const float*)d_in[1];
  const float* deltas   = (const float*)d_in[2];
  const float* label    = (const float*)d_in[3];
  const float* is_train = (const float*)d_in[4];
  const float* W_ih     = (const float*)d_in[5];
  const float* W_hh     = (const float*)d_in[6];
  const float* b_ih     = (const float*)d_in[7];
  const float* b_hh     = (const float*)d_in[8];
  const float* hist_W   = (const float*)d_in[9];
  const float* hist_b   = (const float*)d_in[10];
  const float* feat_W   = (const float*)d_in[11];
  const float* feat_b   = (const float*)d_in[12];
  const float* decay_W  = (const float*)d_in[13];
  const float* decay_b  = (const float*)d_in[14];
  const float* comb_W   = (const float*)d_in[15];
  const float* comb_b   = (const float*)d_in[16];
  const float* out_W    = (const float*)d_in[17];
  const float* out_b    = (const float*)d_in[18];

  float* ws = (float*)d_ws;
  float* rmsum = ws + 4;
  float* out = (float*)d_out;

  hipMemsetAsync(d_ws, 0, 16, stream);
  msum_k<<<Tn, 256, 0, stream>>>((const float4*)masks, rmsum);
  brits_main<<<Bsz / ROWS, 512, 0, stream>>>(
      values, masks, deltas, label, is_train, W_ih, W_hh, b_ih, b_hh,
      hist_W, hist_b, feat_W, feat_b, decay_W, decay_b, comb_W, comb_b,
      out_W, out_b, out, rmsum, ws);
  fin_k<<<1, 1, 0, stream>>>(ws, out);
}

// Round 12
// 426.204 us; speedup vs baseline: 2.7512x; 1.0754x over previous
//
#include <hip/hip_runtime.h>
#include <hip/hip_bf16.h>

// BRITS-style RNN (B=4096, T=256, D=36, H=64) on gfx950.
// R12: R11 + feat-GEMM linearized off the h-critical path.
// Identity: vc1 = m*v + (1-m)*vx  =>  Z = vc1@Wf0^T = MV + vx*(wfsum - Msum),
// MV=(m*v)@Wf0^T, Msum=m@Wf0^T, wfsum=rowsum(Wf0) - ALL h-independent, so they
// are computed one step ahead in S-P2 (from staged m, m*v) and carried as 6
// scalars/lane. S-P1 collapses to: ds_read hbuf -> 2 MFMA (vx) -> per-col VALU
// (vz/vh/vc2/il) -> write vc2. vcbuf deleted (no LDS round-trip in S-P1).
// il factored: srm*m*(|vx-v|+|vz-v|+|vh-v|). Staging also writes m*v frags
// (mvbuf). Msum/MV read through zero-padded B-frags (stale gamma x 0 benign).
// Roles: G-waves 0-3: P1 gh(6)+gi-kt0/1(6)+staging; P2 gi-kt2/3(6)+GRU+hbuf.
// S-waves 4-7 (rows {s,4+s,8+s,12+s}, acc slot q=sW): P1 vx+impute chain;
// P2 Gm(6)+Msum(6)+MV(6)+comb(9)+gamma/beta for t+1. 2 barriers/step.
// Grid 256 = 1 block/CU (co-residency proven unreachable R4/R5/R7/R9).

#define Bsz 4096
#define Tn  256
#define Dn  36
#define ROWS 16
#define EPSf 1e-5f
#define VMST 38

using f32x4 = __attribute__((ext_vector_type(4))) float;
using s8    = __attribute__((ext_vector_type(8))) short;

__device__ __forceinline__ short f2bf(float x) {
  return (short)__bfloat16_as_ushort(__float2bfloat16(x));
}
__device__ __forceinline__ float sigf(float x) { return 1.f / (1.f + __expf(-x)); }
__device__ __forceinline__ float tanhfast(float x) { return 1.f - 2.f / (1.f + __expf(2.f * x)); }
// fragment-linear offset for element (row, k) of an MFMA A-tile (16 rows, bf16)
__device__ __forceinline__ int fragoff(int row, int k) {
  return ((k >> 5) << 9) + (((k >> 3) & 3) << 7) + (row << 3) + (k & 7);
}
// v[s] for wave-uniform runtime s without scratch
__device__ __forceinline__ float selq(f32x4 v, int s) {
  float a = (s & 1) ? v[1] : v[0];
  float b = (s & 1) ? v[3] : v[2];
  return (s & 2) ? b : a;
}
#define MFMA __builtin_amdgcn_mfma_f32_16x16x32_bf16

// ---------------- prepass: rmsum[t] = 1/(sum(masks[:,t,:]) + EPS) -------------
__global__ void msum_k(const float4* __restrict__ masks4, float* __restrict__ rmsum) {
  int t = blockIdx.x;
  float s = 0.f;
  for (int r = threadIdx.x; r < Bsz; r += 256) {
    const float4* mp = masks4 + ((size_t)r * Tn + t) * 9;
    #pragma unroll
    for (int j = 0; j < 9; ++j) { float4 v = mp[j]; s += v.x + v.y + v.z + v.w; }
  }
  __shared__ float red[256];
  red[threadIdx.x] = s;
  __syncthreads();
  for (int k = 128; k > 0; k >>= 1) {
    if (threadIdx.x < k) red[threadIdx.x] += red[threadIdx.x + k];
    __syncthreads();
  }
  if (threadIdx.x == 0) rmsum[t] = 1.f / (red[0] + EPSf);
}

// ---------------- main ---------------------------------------------------------
__global__ __launch_bounds__(512) void brits_main(
    const float* __restrict__ values, const float* __restrict__ masks,
    const float* __restrict__ deltas, const float* __restrict__ label,
    const float* __restrict__ is_train,
    const float* __restrict__ W_ih, const float* __restrict__ W_hh,
    const float* __restrict__ b_ih, const float* __restrict__ b_hh,
    const float* __restrict__ hist_W, const float* __restrict__ hist_b,
    const float* __restrict__ feat_W, const float* __restrict__ feat_b,
    const float* __restrict__ decay_W, const float* __restrict__ decay_b,
    const float* __restrict__ comb_W, const float* __restrict__ comb_b,
    const float* __restrict__ out_W, const float* __restrict__ out_b,
    float* __restrict__ out, const float* __restrict__ rmsum,
    float* __restrict__ ws_acc /* [0] il, [1] cls, [2] wsum */) {

  __shared__ __align__(16) float2 vm_s[2][ROWS * VMST];  // (value, mask)
  __shared__ __align__(16) short hbuf[1024];        // h bf16, K=64 frag-linear
  __shared__ __align__(16) short dbuf[2][1024];     // delta, parity-buffered
  __shared__ __align__(16) short mvbuf[2][1024];    // m*v bf16, parity-buffered
  __shared__ __align__(16) short xbuf[2][2048];     // [mask|gamma|vc2|pad] K=128
  __shared__ float red_s[512];
  __shared__ float red16[16];

  const int tid  = threadIdx.x;
  const int w    = tid >> 6;        // wave 0..7
  const int lane = tid & 63;
  const int lc   = lane & 15;
  const int r4   = lane >> 4;
  const int row0 = blockIdx.x * ROWS;
  const int k0b  = r4 * 8;
  const int lw8  = lane * 8;

  const bool isG = (w < 4);
  const int  sW  = isG ? 0 : (w - 4);
  const int  dim = 16 * (isG ? w : 0) + lc;
  const int  myrow = 4 * r4 + sW;

  // ---- role-overlaid VGPR weight fragments ----
  // G: bf[0..11] = wih (xbuf k-space remap), bf[12..17] = whh
  // S: bf[0..5]=dec, bf[6..11]=feat(zero diag), bf[12..13]=hist(all cols),
  //    bf[14..22]=comb remapped to xbuf k-space
  s8 bf[23];
  #pragma unroll
  for (int i = 0; i < 23; ++i) bf[i] = (s8)(short)0;

  if (isG) {
    #pragma unroll
    for (int g = 0; g < 3; ++g) {
      const int n = 64 * g + dim;
      #pragma unroll
      for (int kt = 0; kt < 4; ++kt) {
        s8 f;
        #pragma unroll
        for (int e = 0; e < 8; ++e) {
          int xk = k0b + 32 * kt + e;
          // xbuf k-space [mask(0:36)|gamma(36:72)|vc2(72:108)|pad]
          // W_ih cols    [vc(0:36)|mask(36:72)|gamma(72:108)]
          float wv = 0.f;
          if (xk < 72) wv = W_ih[n * 108 + 36 + xk];
          else if (xk < 108) wv = W_ih[n * 108 + xk - 72];
          f[e] = f2bf(wv);
        }
        bf[g * 4 + kt] = f;
      }
      #pragma unroll
      for (int kt = 0; kt < 2; ++kt) {
        s8 f;
        #pragma unroll
        for (int e = 0; e < 8; ++e) f[e] = f2bf(W_hh[n * 64 + k0b + 32 * kt + e]);
        bf[12 + g * 2 + kt] = f;
      }
    }
  } else {
    #pragma unroll
    for (int t3 = 0; t3 < 3; ++t3) {
      const int col = 16 * t3 + lc;
      const bool cok = (col < Dn);
      #pragma unroll
      for (int kt = 0; kt < 2; ++kt) {
        s8 fd, ff;
        #pragma unroll
        for (int e = 0; e < 8; ++e) {
          int k = k0b + 32 * kt + e;
          fd[e] = f2bf((cok && k < Dn) ? decay_W[col * Dn + k] : 0.f);
          ff[e] = f2bf((cok && k < Dn && k != col) ? feat_W[col * Dn + k] : 0.f);
        }
        bf[t3 * 2 + kt] = fd;
        bf[6 + t3 * 2 + kt] = ff;
      }
      #pragma unroll
      for (int kt = 0; kt < 3; ++kt) {
        s8 f;
        #pragma unroll
        for (int e = 0; e < 8; ++e) {
          int xk = k0b + 32 * kt + e;
          float wv = 0.f;
          if (cok) {
            if (xk < 36) wv = comb_W[col * 72 + 36 + xk];       // mask part
            else if (xk < 72) wv = comb_W[col * 72 + xk - 36];  // gamma part
          }
          f[e] = f2bf(wv);
        }
        bf[14 + t3 * 3 + kt] = f;
      }
    }
    #pragma unroll
    for (int kt = 0; kt < 2; ++kt) {
      s8 f;
      #pragma unroll
      for (int e = 0; e < 8; ++e) f[e] = f2bf(hist_W[k0b + 32 * kt + e]);
      bf[12 + kt] = f;
    }
  }

  // per-lane constants
  float db3[3] = {0,0,0}, fb3[3] = {0,0,0}, cb3[3] = {0,0,0}, wfs3[3] = {0,0,0};
  float br = 0.f, bz = 0.f, bin_ = 0.f, bhn = 0.f, ow = 0.f;
  if (isG) {
    br   = b_ih[dim] + b_hh[dim];
    bz   = b_ih[64 + dim] + b_hh[64 + dim];
    bin_ = b_ih[128 + dim];
    bhn  = b_hh[128 + dim];
    ow   = out_W[dim];
  } else {
    #pragma unroll
    for (int t3 = 0; t3 < 3; ++t3) {
      int col = 16 * t3 + lc;
      if (col < Dn) {
        db3[t3] = decay_b[col]; fb3[t3] = feat_b[col]; cb3[t3] = comb_b[col];
        float s = 0.f;
        for (int k = 0; k < Dn; ++k) if (k != col) s += feat_W[col * Dn + k];
        wfs3[t3] = s;
      }
    }
  }
  const float histb = hist_b[0];
  const int hb = fragoff(0, dim);

  // staging geometry (G waves, tids 0..143): 16 rows x 9 quads
  const bool stg = (tid < 144);
  const int srow = tid / 9;
  const int squad = tid - srow * 9;
  const size_t sbase = ((size_t)(row0 + srow) * Tn) * Dn + squad * 4;
  const int sfo = fragoff(srow, squad * 4);
  const int svo = srow * VMST + squad * 4;

  // ---- init LDS ----
  for (int i = tid; i < 1024; i += 512) {
    hbuf[i] = 0; dbuf[0][i] = 0; dbuf[1][i] = 0;
    mvbuf[0][i] = 0; mvbuf[1][i] = 0;
  }
  for (int i = tid; i < 2048; i += 512) { xbuf[0][i] = 0; xbuf[1][i] = 0; }
  __syncthreads();

  // ---- prologue: stage t=0 (parity 0), prefetch t=1 ----
  float4 pv = {0,0,0,0}, pm = {0,0,0,0}, pd = {0,0,0,0};
  if (stg) {
    float4 v0 = *(const float4*)&values[sbase];
    float4 m0 = *(const float4*)&masks[sbase];
    float4 d0 = *(const float4*)&deltas[sbase];
    *(float4*)&vm_s[0][svo]     = make_float4(v0.x, m0.x, v0.y, m0.y);
    *(float4*)&vm_s[0][svo + 2] = make_float4(v0.z, m0.z, v0.w, m0.w);
    union { short s[4]; uint2 u; } td, tm, tv;
    td.s[0]=f2bf(d0.x); td.s[1]=f2bf(d0.y); td.s[2]=f2bf(d0.z); td.s[3]=f2bf(d0.w);
    tm.s[0]=f2bf(m0.x); tm.s[1]=f2bf(m0.y); tm.s[2]=f2bf(m0.z); tm.s[3]=f2bf(m0.w);
    tv.s[0]=f2bf(m0.x*v0.x); tv.s[1]=f2bf(m0.y*v0.y);
    tv.s[2]=f2bf(m0.z*v0.z); tv.s[3]=f2bf(m0.w*v0.w);
    *(uint2*)&dbuf[0][sfo] = td.u;
    *(uint2*)&xbuf[0][sfo] = tm.u;
    *(uint2*)&mvbuf[0][sfo] = tv.u;
    pv = *(const float4*)&values[sbase + Dn];
    pm = *(const float4*)&masks[sbase + Dn];
    pd = *(const float4*)&deltas[sbase + Dn];
  }
  __syncthreads();

  float bq[3] = {0,0,0}, mvv[3] = {0,0,0}, msv[3] = {0,0,0};
  // S prologue for t=0: Gm/gamma -> xbuf[0]; Msum/MV; comb/beta
  if (!isG) {
    s8 ad0 = *(const s8*)&dbuf[0][lw8];
    s8 ad1 = *(const s8*)&dbuf[0][512 + lw8];
    s8 am0 = *(const s8*)&xbuf[0][lw8];
    s8 am1 = *(const s8*)&xbuf[0][512 + lw8];
    s8 av0 = *(const s8*)&mvbuf[0][lw8];
    s8 av1 = *(const s8*)&mvbuf[0][512 + lw8];
    f32x4 G0={0,0,0,0}, G1={0,0,0,0}, G2={0,0,0,0};
    f32x4 S0={0,0,0,0}, S1={0,0,0,0}, S2={0,0,0,0};
    f32x4 V0={0,0,0,0}, V1={0,0,0,0}, V2={0,0,0,0};
    G0 = MFMA(ad0, bf[0], G0, 0,0,0); G0 = MFMA(ad1, bf[1], G0, 0,0,0);
    G1 = MFMA(ad0, bf[2], G1, 0,0,0); G1 = MFMA(ad1, bf[3], G1, 0,0,0);
    G2 = MFMA(ad0, bf[4], G2, 0,0,0); G2 = MFMA(ad1, bf[5], G2, 0,0,0);
    S0 = MFMA(am0, bf[6], S0, 0,0,0); S0 = MFMA(am1, bf[7], S0, 0,0,0);
    S1 = MFMA(am0, bf[8], S1, 0,0,0); S1 = MFMA(am1, bf[9], S1, 0,0,0);
    S2 = MFMA(am0, bf[10], S2, 0,0,0); S2 = MFMA(am1, bf[11], S2, 0,0,0);
    V0 = MFMA(av0, bf[6], V0, 0,0,0); V0 = MFMA(av1, bf[7], V0, 0,0,0);
    V1 = MFMA(av0, bf[8], V1, 0,0,0); V1 = MFMA(av1, bf[9], V1, 0,0,0);
    V2 = MFMA(av0, bf[10], V2, 0,0,0); V2 = MFMA(av1, bf[11], V2, 0,0,0);
    #pragma unroll
    for (int t3 = 0; t3 < 3; ++t3) {
      int col = 16 * t3 + lc;
      if (col < Dn) {
        float gm = (t3==0) ? selq(G0,sW) : (t3==1) ? selq(G1,sW) : selq(G2,sW);
        xbuf[0][fragoff(myrow, 36 + col)] = f2bf(__expf(-fmaxf(gm + db3[t3], 0.f)));
      }
      msv[t3] = (t3==0) ? selq(S0,sW) : (t3==1) ? selq(S1,sW) : selq(S2,sW);
      mvv[t3] = (t3==0) ? selq(V0,sW) : (t3==1) ? selq(V1,sW) : selq(V2,sW);
    }
    s8 ac1 = *(const s8*)&xbuf[0][512 + lw8];
    s8 ac2 = *(const s8*)&xbuf[0][1024 + lw8];
    f32x4 B0={0,0,0,0}, B1={0,0,0,0}, B2={0,0,0,0};
    B0 = MFMA(am0, bf[14], B0, 0,0,0); B0 = MFMA(ac1, bf[15], B0, 0,0,0);
    B0 = MFMA(ac2, bf[16], B0, 0,0,0);
    B1 = MFMA(am0, bf[17], B1, 0,0,0); B1 = MFMA(ac1, bf[18], B1, 0,0,0);
    B1 = MFMA(ac2, bf[19], B1, 0,0,0);
    B2 = MFMA(am0, bf[20], B2, 0,0,0); B2 = MFMA(ac1, bf[21], B2, 0,0,0);
    B2 = MFMA(ac2, bf[22], B2, 0,0,0);
    bq[0] = sigf(selq(B0,sW) + cb3[0]);
    bq[1] = sigf(selq(B1,sW) + cb3[1]);
    bq[2] = sigf(selq(B2,sW) + cb3[2]);
  }

  float hreg[4] = {0.f, 0.f, 0.f, 0.f};
  float lacc[4] = {0.f, 0.f, 0.f, 0.f};
  float il = 0.f;
  __syncthreads();

  #pragma unroll 2
  for (int t = 0; t < Tn; ++t) {
    const float srm = rmsum[t];
    const int p = t & 1;                 // folds per unrolled clone
    short* __restrict__ xb  = xbuf[p];
    short* __restrict__ xb2 = xbuf[p ^ 1];
    short* __restrict__ db2 = dbuf[p ^ 1];
    short* __restrict__ mv2 = mvbuf[p ^ 1];
    f32x4 A0 = {0,0,0,0}, A1 = {0,0,0,0}, A2 = {0,0,0,0}, A3 = {0,0,0,0};

    // ================ P1 ================
    if (isG) {
      s8 ah0 = *(const s8*)&hbuf[lw8];
      s8 ah1 = *(const s8*)&hbuf[512 + lw8];
      A0 = MFMA(ah0, bf[12], A0, 0,0,0); A0 = MFMA(ah1, bf[13], A0, 0,0,0);
      A1 = MFMA(ah0, bf[14], A1, 0,0,0); A1 = MFMA(ah1, bf[15], A1, 0,0,0);
      A3 = MFMA(ah0, bf[16], A3, 0,0,0); A3 = MFMA(ah1, bf[17], A3, 0,0,0);
      s8 ax0 = *(const s8*)&xb[lw8];
      s8 ax1 = *(const s8*)&xb[512 + lw8];
      A0 = MFMA(ax0, bf[0], A0, 0,0,0); A0 = MFMA(ax1, bf[1], A0, 0,0,0);
      A1 = MFMA(ax0, bf[4], A1, 0,0,0); A1 = MFMA(ax1, bf[5], A1, 0,0,0);
      A2 = MFMA(ax0, bf[8], A2, 0,0,0); A2 = MFMA(ax1, bf[9], A2, 0,0,0);
      // stage t+1 into parity p^1
      if (stg && t + 1 < Tn) {
        *(float4*)&vm_s[p ^ 1][svo]     = make_float4(pv.x, pm.x, pv.y, pm.y);
        *(float4*)&vm_s[p ^ 1][svo + 2] = make_float4(pv.z, pm.z, pv.w, pm.w);
        union { short s[4]; uint2 u; } td, tm, tv;
        td.s[0]=f2bf(pd.x); td.s[1]=f2bf(pd.y); td.s[2]=f2bf(pd.z); td.s[3]=f2bf(pd.w);
        tm.s[0]=f2bf(pm.x); tm.s[1]=f2bf(pm.y); tm.s[2]=f2bf(pm.z); tm.s[3]=f2bf(pm.w);
        tv.s[0]=f2bf(pm.x*pv.x); tv.s[1]=f2bf(pm.y*pv.y);
        tv.s[2]=f2bf(pm.z*pv.z); tv.s[3]=f2bf(pm.w*pv.w);
        *(uint2*)&db2[sfo] = td.u;
        *(uint2*)&xb2[sfo] = tm.u;
        *(uint2*)&mv2[sfo] = tv.u;
      }
      if (stg && t + 2 < Tn) {
        size_t o = sbase + (size_t)(t + 2) * Dn;
        pv = *(const float4*)&values[o];
        pm = *(const float4*)&masks[o];
        pd = *(const float4*)&deltas[o];
      }
    } else {
      // ---- S: h-critical chain: vx MFMA then pure VALU (no LDS round-trip) ----
      s8 ah0 = *(const s8*)&hbuf[lw8];
      s8 ah1 = *(const s8*)&hbuf[512 + lw8];
      f32x4 X = {0,0,0,0};
      X = MFMA(ah0, bf[12], X, 0,0,0);
      X = MFMA(ah1, bf[13], X, 0,0,0);
      const float vx = selq(X, sW) + histb;
      #pragma unroll
      for (int t3 = 0; t3 < 3; ++t3) {
        int col = 16 * t3 + lc;
        if (col < Dn) {
          float2 vm = vm_s[p][myrow * VMST + col];
          float vz = vx * (wfs3[t3] - msv[t3]) + mvv[t3] + fb3[t3];
          float vh = vz * bq[t3] + vx * (1.f - bq[t3]);
          float vc2 = vm.y * vm.x + (1.f - vm.y) * vh;
          il += srm * vm.y *
                (fabsf(vx - vm.x) + fabsf(vz - vm.x) + fabsf(vh - vm.x));
          out[1 + ((size_t)(row0 + myrow) * Tn + t) * Dn + col] = vc2;
          xb[fragoff(myrow, 72 + col)] = f2bf(vc2);
        }
      }
    }
    __syncthreads();  // b1: vc2 + staged t+1 visible

    // ================ P2 ================
    if (isG) {
      s8 ax2 = *(const s8*)&xb[1024 + lw8];
      s8 ax3 = *(const s8*)&xb[1536 + lw8];
      A0 = MFMA(ax2, bf[2],  A0, 0,0,0); A0 = MFMA(ax3, bf[3],  A0, 0,0,0);
      A1 = MFMA(ax2, bf[6],  A1, 0,0,0); A1 = MFMA(ax3, bf[7],  A1, 0,0,0);
      A2 = MFMA(ax2, bf[10], A2, 0,0,0); A2 = MFMA(ax3, bf[11], A2, 0,0,0);
      #pragma unroll
      for (int q = 0; q < 4; ++q) {
        float rg = sigf(A0[q] + br);
        float zg = sigf(A1[q] + bz);
        float ng = tanhfast(A2[q] + bin_ + rg * (A3[q] + bhn));
        float hn = (1.f - zg) * ng + zg * hreg[q];
        hreg[q] = hn;
        lacc[q] += hn * ow;
        hbuf[hb + (r4 * 4 + q) * 8] = f2bf(hn);
      }
    } else if (t + 1 < Tn) {
      // ---- S: precompute for t+1: Gm/gamma, Msum, MV, comb/beta ----
      s8 ad0 = *(const s8*)&db2[lw8];
      s8 ad1 = *(const s8*)&db2[512 + lw8];
      s8 am0 = *(const s8*)&xb2[lw8];
      s8 am1 = *(const s8*)&xb2[512 + lw8];   // stale gamma x zero weight: benign
      s8 av0 = *(const s8*)&mv2[lw8];
      s8 av1 = *(const s8*)&mv2[512 + lw8];
      f32x4 G0={0,0,0,0}, G1={0,0,0,0}, G2={0,0,0,0};
      f32x4 S0={0,0,0,0}, S1={0,0,0,0}, S2={0,0,0,0};
      f32x4 V0={0,0,0,0}, V1={0,0,0,0}, V2={0,0,0,0};
      G0 = MFMA(ad0, bf[0], G0, 0,0,0); G0 = MFMA(ad1, bf[1], G0, 0,0,0);
      G1 = MFMA(ad0, bf[2], G1, 0,0,0); G1 = MFMA(ad1, bf[3], G1, 0,0,0);
      G2 = MFMA(ad0, bf[4], G2, 0,0,0); G2 = MFMA(ad1, bf[5], G2, 0,0,0);
      S0 = MFMA(am0, bf[6], S0, 0,0,0); S0 = MFMA(am1, bf[7], S0, 0,0,0);
      S1 = MFMA(am0, bf[8], S1, 0,0,0); S1 = MFMA(am1, bf[9], S1, 0,0,0);
      S2 = MFMA(am0, bf[10], S2, 0,0,0); S2 = MFMA(am1, bf[11], S2, 0,0,0);
      V0 = MFMA(av0, bf[6], V0, 0,0,0); V0 = MFMA(av1, bf[7], V0, 0,0,0);
      V1 = MFMA(av0, bf[8], V1, 0,0,0); V1 = MFMA(av1, bf[9], V1, 0,0,0);
      V2 = MFMA(av0, bf[10], V2, 0,0,0); V2 = MFMA(av1, bf[11], V2, 0,0,0);
      #pragma unroll
      for (int t3 = 0; t3 < 3; ++t3) {
        int col = 16 * t3 + lc;
        if (col < Dn) {
          float gm = (t3==0) ? selq(G0,sW) : (t3==1) ? selq(G1,sW) : selq(G2,sW);
          xb2[fragoff(myrow, 36 + col)] = f2bf(__expf(-fmaxf(gm + db3[t3], 0.f)));
        }
        msv[t3] = (t3==0) ? selq(S0,sW) : (t3==1) ? selq(S1,sW) : selq(S2,sW);
        mvv[t3] = (t3==0) ? selq(V0,sW) : (t3==1) ? selq(V1,sW) : selq(V2,sW);
      }
      // comb reads xb2: kt0 = mask only (am0 reusable), kt1/kt2 re-read after
      // gamma writes (same-wave lgkmcnt ordering); vc2-stale x 0 = benign
      s8 ac1 = *(const s8*)&xb2[512 + lw8];
      s8 ac2 = *(const s8*)&xb2[1024 + lw8];
      f32x4 B0={0,0,0,0}, B1={0,0,0,0}, B2={0,0,0,0};
      B0 = MFMA(am0, bf[14], B0, 0,0,0); B0 = MFMA(ac1, bf[15], B0, 0,0,0);
      B0 = MFMA(ac2, bf[16], B0, 0,0,0);
      B1 = MFMA(am0, bf[17], B1, 0,0,0); B1 = MFMA(ac1, bf[18], B1, 0,0,0);
      B1 = MFMA(ac2, bf[19], B1, 0,0,0);
      B2 = MFMA(am0, bf[20], B2, 0,0,0); B2 = MFMA(ac1, bf[21], B2, 0,0,0);
      B2 = MFMA(ac2, bf[22], B2, 0,0,0);
      bq[0] = sigf(selq(B0,sW) + cb3[0]);
      bq[1] = sigf(selq(B1,sW) + cb3[1]);
      bq[2] = sigf(selq(B2,sW) + cb3[2]);
    }
    __syncthreads();  // b2: h(t) + gamma(t+1) visible
  }

  // ---- epilogue: reduce il, logits, pred, class loss ----
  red_s[tid] = il;
  __syncthreads();
  for (int k = 256; k > 0; k >>= 1) {
    if (tid < k) red_s[tid] += red_s[tid + k];
    __syncthreads();
  }
  if (tid == 0) atomicAdd(&ws_acc[0], red_s[0]);
  if (tid < 16) red16[tid] = 0.f;
  __syncthreads();
  if (isG) {
    #pragma unroll
    for (int q = 0; q < 4; ++q) atomicAdd(&red16[r4 * 4 + q], lacc[q]);
  }
  __syncthreads();

  if (tid < ROWS) {
    float lg = red16[tid] / (float)Tn + out_b[0];
    int rg = row0 + tid;
    float pred = sigf(lg);
    out[1 + (size_t)Bsz * Tn * Dn + rg] = pred;
    float y = label[rg], wt = is_train[rg];
    float bce = fmaxf(lg, 0.f) - lg * y + log1pf(__expf(-fabsf(lg)));
    atomicAdd(&ws_acc[1], bce * wt);
    atomicAdd(&ws_acc[2], wt);
  }
}

// ---------------- finalize loss -------------------------------------------------
__global__ void fin_k(const float* __restrict__ ws, float* __restrict__ out) {
  out[0] = ws[1] / (ws[2] + EPSf) + ws[0] / (float)Tn;
}

extern "C" void kernel_launch(void* const* d_in, const int* in_sizes, int n_in,
                              void* d_out, int out_size, void* d_ws, size_t ws_size,
                              hipStream_t stream) {
  const float* values   = (const float*)d_in[0];
  const float* masks    = (const float*)d_in[1];
  const float* deltas   = (const float*)d_in[2];
  const float* label    = (const float*)d_in[3];
  const float* is_train = (const float*)d_in[4];
  const float* W_ih     = (const float*)d_in[5];
  const float* W_hh     = (const float*)d_in[6];
  const float* b_ih     = (const float*)d_in[7];
  const float* b_hh     = (const float*)d_in[8];
  const float* hist_W   = (const float*)d_in[9];
  const float* hist_b   = (const float*)d_in[10];
  const float* feat_W   = (const float*)d_in[11];
  const float* feat_b   = (const float*)d_in[12];
  const float* decay_W  = (const float*)d_in[13];
  const float* decay_b  = (const float*)d_in[14];
  const float* comb_W   = (const float*)d_in[15];
  const float* comb_b   = (const float*)d_in[16];
  const float* out_W    = (const float*)d_in[17];
  const float* out_b    = (const float*)d_in[18];

  float* ws = (float*)d_ws;
  float* rmsum = ws + 4;
  float* out = (float*)d_out;

  hipMemsetAsync(d_ws, 0, 16, stream);
  msum_k<<<Tn, 256, 0, stream>>>((const float4*)masks, rmsum);
  brits_main<<<Bsz / ROWS, 512, 0, stream>>>(
      values, masks, deltas, label, is_train, W_ih, W_hh, b_ih, b_hh,
      hist_W, hist_b, feat_W, feat_b, decay_W, decay_b, comb_W, comb_b,
      out_W, out_b, out, rmsum, ws);
  fin_k<<<1, 1, 0, stream>>>(ws, out);
}